// Round 6
// baseline (1969.546 us; speedup 1.0000x reference)
//
#include <hip/hip_runtime.h>
#include <hip/hip_bf16.h>

typedef __hip_bfloat16 bf16;

// B=8, C=256, H=W=64, nh=4, HD=64, coarse tokens N=1024 (32x32), kf=256, fine tokens 1024.
// Inputs/outputs: dtype auto-detected (all evidence says fp32; bf16 path kept as insurance).

// ---------------- workspace layout (float offsets), peak 86.5 MB ----------------
#define OFF_XDHWC    0L
#define OFF_Q        2097152L
#define OFF_KK       4194304L
#define OFF_V        6291456L
#define OFF_T1       0L           // overlay on trunk (XDHWC/Q/K/V dead)
#define OFF_OUTC     8388608L
#define OFF_COARSE   10485760L    // xf (fp32 x) first, then coarse NCHW -> y
#define OFF_XF       10485760L
#define OFF_PSC      18874368L
#define OFF_SCORE    19398656L
#define OFF_TOPK     19431424L
#define OFF_DOWNW    19439616L
#define OFF_UPW4     20488192L
#define OFF_WQKVC    21536768L
#define OFF_BQKVC    21549056L
#define OFF_WQKVF    21549248L
#define OFF_BQKVF    21561536L
#define OFF_PWW      21561728L
#define OFF_DWW      21627264L
#define OFF_BN1S     21629568L
#define OFF_BN1T     21629824L
#define OFF_BN2S     21630080L
#define OFF_BN2T     21630336L
#define OFF_DOWNB    21630592L
#define OFF_UPB      21630848L
#define OFF_FLAG     21631104L    // 1 int: 1 = bf16 world, 0 = fp32 world (default via memset)
#define WS_FLOATS    21631360L

// NaN-preserving relu6 (identical for finite v; NaN propagates as a diagnostic)
__device__ __forceinline__ float relu6(float v) { return v < 0.f ? 0.f : (v > 6.f ? 6.f : v); }

__device__ __forceinline__ float ldin(const void* p, long i, int flag) {
    return flag ? __bfloat162float(((const bf16*)p)[i]) : ((const float*)p)[i];
}

// ---------------- dtype detector ----------------
// bf16 N(0,1): ~100% of bf16-view samples in (1e-8,100). fp32 viewed as bf16: ~56%. Threshold 90%.
__global__ __launch_bounds__(256) void detect_kernel(const void* __restrict__ x, int* __restrict__ flag) {
    __shared__ int cnt[256];
    int tid = threadIdx.x;
    int c = 0;
    for (int i = tid; i < 4096; i += 256) {
        long idx = (long)i * 2047;   // spread over [0, 8.38M) bf16 elems (in-bounds both worlds)
        float v = __bfloat162float(((const bf16*)x)[idx]);
        float a = fabsf(v);
        if (isfinite(v) && a > 1e-8f && a < 100.f) c++;
    }
    cnt[tid] = c; __syncthreads();
    for (int s = 128; s > 0; s >>= 1) { if (tid < s) cnt[tid] += cnt[tid + s]; __syncthreads(); }
    if (tid == 0 && cnt[0] >= 3686) *flag = 1;
}

// ---------------- prep kernels (dual-dtype) ----------------
__global__ __launch_bounds__(256) void cvt_kernel(const void* __restrict__ in, float* __restrict__ out,
                                                  int n, const int* __restrict__ flagp) {
    int flag = *flagp;
    int i = blockIdx.x * 256 + threadIdx.x;
    if (i < n) out[i] = ldin(in, i, flag);
}

__global__ __launch_bounds__(256) void tqkv_kernel(const void* __restrict__ w, float* __restrict__ wt,
                                                   const int* __restrict__ flagp) {
    int flag = *flagp;
    int idx = blockIdx.x * 256 + threadIdx.x;
    if (idx >= 192 * 64) return;
    int j = idx >> 6, d = idx & 63;
    wt[idx] = ldin(w, d * 192 + j, flag);
}

// up_w [ci,co,4,4] -> W4 [cls][co][ci*4+j]
// parity a=0: jy=0->(ky=1,dy=0), jy=1->(ky=3,dy=-1); a=1: jy=0->(ky=2,dy=0), jy=1->(ky=0,dy=+1)
__global__ __launch_bounds__(256) void prep_up_kernel(const void* __restrict__ w, float* __restrict__ W4,
                                                      const int* __restrict__ flagp) {
    int flag = *flagp;
    int idx = blockIdx.x * 256 + threadIdx.x;
    int cls = idx >> 18; int rem = idx & 262143;
    int co = rem >> 10; int q = rem & 1023;
    int ci = q >> 2; int j = q & 3;
    int pa = cls >> 1, pb = cls & 1;
    int jy = j >> 1, jx = j & 1;
    int ky = (pa == 0) ? (jy ? 3 : 1) : (jy ? 0 : 2);
    int kx = (pb == 0) ? (jx ? 3 : 1) : (jx ? 0 : 2);
    W4[idx] = ldin(w, (((long)ci * 256 + co) * 4 + ky) * 4 + kx, flag);
}

__global__ void bn_prep_kernel(const void* __restrict__ g, const void* __restrict__ b,
                               const void* __restrict__ m, const void* __restrict__ v,
                               float* __restrict__ s, float* __restrict__ t,
                               const int* __restrict__ flagp) {
    int flag = *flagp;
    int c = threadIdx.x;
    float gv = ldin(g, c, flag), bv = ldin(b, c, flag);
    float mv = ldin(m, c, flag), vv = ldin(v, c, flag);
    float inv = gv / sqrtf(vv + 1e-5f);
    s[c] = inv; t[c] = bv - mv * inv;
}

// ---------------- generic GEMM: C[m,n] = sum_k A[m,k]*B[n,k]; B k-contiguous ----------------
// AMODE: 0 strided A; 1 implicit im2col from fp32 XF (down conv); 2 implicit im2col from OUTC (up conv, z=cls)
// EPI: 1 +bias; 2/3 qkv split (coarse/fine m-map); 4 conv-T scatter NCHW; 5 bn+relu6 -> d_out (dtype per flag)
template<int EPI, int AMODE>
__global__ __launch_bounds__(256) void gemm_k(
    const float* __restrict__ A, const float* __restrict__ B, float* __restrict__ C,
    int K, long sAz, long sBz, int sAm, int sAk, int sBn,
    const float* __restrict__ e0, const float* __restrict__ e1,
    float* __restrict__ o1, float* __restrict__ o2, void* __restrict__ ob,
    const int* __restrict__ flagp)
{
    __shared__ float As[16][64];
    __shared__ float Bs[16][64];
    int z = blockIdx.z;
    if (AMODE == 0) A += (long)z * sAz;
    B += (long)z * sBz;
    int m0 = blockIdx.y * 64;
    int n0 = blockIdx.x * 64;
    int tid = threadIdx.x;
    int tx = tid & 15, ty = tid >> 4;
    float acc[4][4] = {};
    for (int k0 = 0; k0 < K; k0 += 16) {
        if (AMODE == 0) {
            if (sAk == 1) {
                for (int i = tid; i < 1024; i += 256) {
                    int kl = i & 15, ml = i >> 4;
                    As[kl][ml] = A[(long)(m0 + ml) * sAm + (k0 + kl)];
                }
            } else {
                for (int i = tid; i < 1024; i += 256) {
                    int ml = i & 63, kl = i >> 6;
                    As[kl][ml] = A[(long)(m0 + ml) * sAm + (long)(k0 + kl) * sAk];
                }
            }
        } else if (AMODE == 1) {  // xf[b,c,iy,ix], m=(b,oy,ox), k=(c,ky,kx)
            for (int i = tid; i < 1024; i += 256) {
                int kl = i & 15, ml = i >> 4;
                int m = m0 + ml, k = k0 + kl;
                int b = m >> 10, oy = (m >> 5) & 31, ox = m & 31;
                int c = k >> 4, ky = (k >> 2) & 3, kx = k & 3;
                int iy = 2 * oy - 1 + ky, ix = 2 * ox - 1 + kx;
                float val = 0.f;
                if ((unsigned)iy < 64u && (unsigned)ix < 64u)
                    val = A[(((long)b * 256 + c) * 64 + iy) * 64 + ix];
                As[kl][ml] = val;
            }
        } else {  // AMODE 2: OUTC[bh,tok,d], m=(b,y,x), k=(ci,j), cls=z
            for (int i = tid; i < 1024; i += 256) {
                int kl = i & 15, ml = i >> 4;
                int m = m0 + ml, k = k0 + kl;
                int b = m >> 10, y = (m >> 5) & 31, x2 = m & 31;
                int ci = k >> 2, j = k & 3;
                int pa = z >> 1, pb = z & 1;
                int jy = j >> 1, jx = j & 1;
                int dy = (pa == 0) ? (jy ? -1 : 0) : (jy ? 1 : 0);
                int dx = (pb == 0) ? (jx ? -1 : 0) : (jx ? 1 : 0);
                int yy = y + dy, xx = x2 + dx;
                float val = 0.f;
                if ((unsigned)yy < 32u && (unsigned)xx < 32u)
                    val = A[(((long)b * 4 + (ci >> 6)) * 1024 + yy * 32 + xx) * 64 + (ci & 63)];
                As[kl][ml] = val;
            }
        }
        for (int i = tid; i < 1024; i += 256) {
            int kl = i & 15, nl = i >> 4;
            Bs[kl][nl] = B[(long)(n0 + nl) * sBn + (k0 + kl)];
        }
        __syncthreads();
        #pragma unroll
        for (int kk = 0; kk < 16; ++kk) {
            float4 av = *reinterpret_cast<const float4*>(&As[kk][ty * 4]);
            float4 bv = *reinterpret_cast<const float4*>(&Bs[kk][tx * 4]);
            float a[4] = {av.x, av.y, av.z, av.w};
            float b[4] = {bv.x, bv.y, bv.z, bv.w};
            #pragma unroll
            for (int i = 0; i < 4; i++)
                #pragma unroll
                for (int j = 0; j < 4; j++)
                    acc[i][j] += a[i] * b[j];
        }
        __syncthreads();
    }
    int oflag = (EPI == 5) ? *flagp : 0;
    #pragma unroll
    for (int i = 0; i < 4; i++) {
        int m = m0 + ty * 4 + i;
        #pragma unroll
        for (int j = 0; j < 4; j++) {
            int n = n0 + tx * 4 + j;
            float v = acc[i][j];
            if (EPI == 1) {
                C[(long)m * 256 + n] = v + e0[n];
            } else if (EPI == 2 || EPI == 3) {
                v += e0[n];
                int bh, tok;
                if (EPI == 2) { int bi = m >> 12; int h = m & 3; tok = (m >> 2) & 1023; bh = bi * 4 + h; }
                else          { bh = m >> 10; tok = m & 1023; }
                long base = ((long)bh * 1024 + tok) * 64;
                if (n < 64) C[base + n] = v;
                else if (n < 128) o1[base + (n - 64)] = v;
                else o2[base + (n - 128)] = v;
            } else if (EPI == 4) {
                v += e0[n];
                int pa = z >> 1, pb = z & 1;
                int bi = m >> 10, y = (m >> 5) & 31, x2 = m & 31;
                C[(((long)bi * 256 + n) * 64 + (2 * y + pa)) * 64 + (2 * x2 + pb)] = v;
            } else if (EPI == 5) {
                v = relu6(v * e0[n] + e1[n]);
                long oidx = (long)z * 1048576 + (long)n * 4096 + m;
                if (oflag) ((bf16*)ob)[oidx] = __float2bfloat16(v);
                else       ((float*)ob)[oidx] = v;
            }
        }
    }
}

// ---------------- fused two-pass attention: [bh=32][N=1024][D=64], scale 1/8 folded into Q ----------------
template<bool SCORE>
__global__ __launch_bounds__(256) void attn_kernel(
    const float* __restrict__ Q, const float* __restrict__ K, const float* __restrict__ V,
    float* __restrict__ O, float* __restrict__ PSC)
{
    __shared__ __align__(16) float QT[64 * 68];
    __shared__ __align__(16) float KV[64 * 68];
    __shared__ __align__(16) float Ps[64 * 68];
    __shared__ float colpart[16 * 64];
    int bh = blockIdx.y, rt = blockIdx.x;
    int tid = threadIdx.x;
    int tx = tid & 15, ty = tid >> 4;
    long qbase = ((long)bh * 1024 + rt * 64) * 64;
    for (int q = tid; q < 1024; q += 256) {
        int r = q >> 4, d4 = (q & 15) * 4;
        float4 v4 = *(const float4*)(Q + qbase + r * 64 + d4);
        QT[(d4 + 0) * 68 + r] = v4.x * 0.125f;
        QT[(d4 + 1) * 68 + r] = v4.y * 0.125f;
        QT[(d4 + 2) * 68 + r] = v4.z * 0.125f;
        QT[(d4 + 3) * 68 + r] = v4.w * 0.125f;
    }
    float m[4], l[4];
    #pragma unroll
    for (int i = 0; i < 4; i++) { m[i] = -1e30f; l[i] = 0.f; }
    __syncthreads();

    for (int t = 0; t < 16; ++t) {   // pass 1: row max + sumexp
        long kbase = ((long)bh * 1024 + t * 64) * 64;
        for (int q = tid; q < 1024; q += 256) {
            int c = q >> 4, d4 = (q & 15) * 4;
            float4 v4 = *(const float4*)(K + kbase + c * 64 + d4);
            KV[(d4 + 0) * 68 + c] = v4.x;
            KV[(d4 + 1) * 68 + c] = v4.y;
            KV[(d4 + 2) * 68 + c] = v4.z;
            KV[(d4 + 3) * 68 + c] = v4.w;
        }
        __syncthreads();
        float zv[4][4] = {};
        for (int d = 0; d < 64; ++d) {
            float4 qa = *(const float4*)(QT + d * 68 + ty * 4);
            float4 kb = *(const float4*)(KV + d * 68 + tx * 4);
            float a[4] = {qa.x, qa.y, qa.z, qa.w};
            float b[4] = {kb.x, kb.y, kb.z, kb.w};
            #pragma unroll
            for (int i = 0; i < 4; i++)
                #pragma unroll
                for (int j = 0; j < 4; j++)
                    zv[i][j] += a[i] * b[j];
        }
        #pragma unroll
        for (int i = 0; i < 4; i++) {
            float tm = fmaxf(fmaxf(zv[i][0], zv[i][1]), fmaxf(zv[i][2], zv[i][3]));
            for (int off = 1; off < 16; off <<= 1) tm = fmaxf(tm, __shfl_xor(tm, off, 16));
            float mn = fmaxf(m[i], tm);
            float ss = __expf(zv[i][0] - mn) + __expf(zv[i][1] - mn) + __expf(zv[i][2] - mn) + __expf(zv[i][3] - mn);
            for (int off = 1; off < 16; off <<= 1) ss += __shfl_xor(ss, off, 16);
            l[i] = l[i] * __expf(m[i] - mn) + ss;
            m[i] = mn;
        }
        __syncthreads();
    }
    float linv[4];
    #pragma unroll
    for (int i = 0; i < 4; i++) linv[i] = 1.f / l[i];

    float Oa[4][4] = {};
    for (int t = 0; t < 16; ++t) {   // pass 2: exact probs, O=P@V, colsums
        long kbase = ((long)bh * 1024 + t * 64) * 64;
        for (int q = tid; q < 1024; q += 256) {
            int c = q >> 4, d4 = (q & 15) * 4;
            float4 v4 = *(const float4*)(K + kbase + c * 64 + d4);
            KV[(d4 + 0) * 68 + c] = v4.x;
            KV[(d4 + 1) * 68 + c] = v4.y;
            KV[(d4 + 2) * 68 + c] = v4.z;
            KV[(d4 + 3) * 68 + c] = v4.w;
        }
        __syncthreads();
        float zv[4][4] = {};
        for (int d = 0; d < 64; ++d) {
            float4 qa = *(const float4*)(QT + d * 68 + ty * 4);
            float4 kb = *(const float4*)(KV + d * 68 + tx * 4);
            float a[4] = {qa.x, qa.y, qa.z, qa.w};
            float b[4] = {kb.x, kb.y, kb.z, kb.w};
            #pragma unroll
            for (int i = 0; i < 4; i++)
                #pragma unroll
                for (int j = 0; j < 4; j++)
                    zv[i][j] += a[i] * b[j];
        }
        float cs[4] = {0.f, 0.f, 0.f, 0.f};
        #pragma unroll
        for (int i = 0; i < 4; i++)
            #pragma unroll
            for (int j = 0; j < 4; j++) {
                float p = __expf(zv[i][j] - m[i]) * linv[i];
                Ps[(ty * 4 + i) * 68 + tx * 4 + j] = p;
                cs[j] += p;
            }
        if (SCORE) {
            #pragma unroll
            for (int j = 0; j < 4; j++) colpart[ty * 64 + tx * 4 + j] = cs[j];
        }
        __syncthreads();
        if (SCORE && tid < 64) {
            float s = 0.f;
            #pragma unroll
            for (int g = 0; g < 16; g++) s += colpart[g * 64 + tid];
            PSC[((long)(bh * 16 + rt) << 10) + t * 64 + tid] = s;
        }
        for (int q = tid; q < 1024; q += 256) {
            int c = q >> 4, d4 = (q & 15) * 4;
            float4 v4 = *(const float4*)(V + kbase + c * 64 + d4);
            *(float4*)(KV + c * 68 + d4) = v4;
        }
        __syncthreads();
        for (int c = 0; c < 64; ++c) {
            float4 vb = *(const float4*)(KV + c * 68 + tx * 4);
            float b[4] = {vb.x, vb.y, vb.z, vb.w};
            float pv[4];
            #pragma unroll
            for (int i = 0; i < 4; i++) pv[i] = Ps[(ty * 4 + i) * 68 + c];
            #pragma unroll
            for (int i = 0; i < 4; i++)
                #pragma unroll
                for (int j = 0; j < 4; j++)
                    Oa[i][j] += pv[i] * b[j];
        }
        __syncthreads();
    }
    #pragma unroll
    for (int i = 0; i < 4; i++) {
        float4 o4 = make_float4(Oa[i][0], Oa[i][1], Oa[i][2], Oa[i][3]);
        *(float4*)(O + qbase + (ty * 4 + i) * 64 + tx * 4) = o4;
    }
}

__global__ __launch_bounds__(256) void score_reduce_kernel(const float* __restrict__ PSC, float* __restrict__ score) {
    int idx = blockIdx.x * 256 + threadIdx.x;
    int bh = idx >> 10, c = idx & 1023;
    float s = 0.f;
    for (int rt = 0; rt < 16; rt++) s += PSC[((long)(bh * 16 + rt) << 10) + c];
    score[idx] = s;
}

// exact top-256 set, stable ranking; NaN->-inf so all slots always written
__global__ __launch_bounds__(256) void topk_kernel(const float* __restrict__ score, int* __restrict__ topk) {
    __shared__ float s[1024];
    int z = blockIdx.x; int tid = threadIdx.x;
    for (int i = tid; i < 1024; i += 256) {
        float v = score[z * 1024 + i];
        s[i] = (v == v) ? v : -INFINITY;
    }
    __syncthreads();
    for (int i = tid; i < 1024; i += 256) {
        float si = s[i]; int r = 0;
        for (int j = 0; j < 1024; j++) {
            float sj = s[j];
            r += (sj > si) || (sj == si && j < i);
        }
        if (r < 256) topk[z * 256 + r] = i;
    }
}

__global__ __launch_bounds__(256) void gather_tokf_kernel(const float* __restrict__ coarse,
                                                          const int* __restrict__ topk,
                                                          float* __restrict__ tokf) {
    long idx = (long)blockIdx.x * 256 + threadIdx.x;
    int d = (int)(idx & 63); int t = (int)((idx >> 6) & 3);
    int j = (int)((idx >> 8) & 255); int bh = (int)(idx >> 16);
    int p = topk[bh * 256 + j] & 1023;
    int py = p >> 5, px = p & 31;
    int dy = t >> 1, dx = t & 1;
    int b = bh >> 2, h = bh & 3;
    tokf[idx] = coarse[(((long)b * 256 + h * 64 + d) * 64 + (2 * py + dy)) * 64 + (2 * px + dx)];
}

__global__ __launch_bounds__(256) void scatter_add_kernel(float* __restrict__ coarse,
                                                          const int* __restrict__ topk,
                                                          const float* __restrict__ outf) {
    long idx = (long)blockIdx.x * 256 + threadIdx.x;
    int d = (int)(idx & 63); int t = (int)((idx >> 6) & 3);
    int j = (int)((idx >> 8) & 255); int bh = (int)(idx >> 16);
    int p = topk[bh * 256 + j] & 1023;
    int py = p >> 5, px = p & 31;
    int dy = t >> 1, dx = t & 1;
    int b = bh >> 2, h = bh & 3;
    coarse[(((long)b * 256 + h * 64 + d) * 64 + (2 * py + dy)) * 64 + (2 * px + dx)] += outf[idx];
}

__global__ __launch_bounds__(64) void dw_bn_relu6_kernel(const float* __restrict__ y, const float* __restrict__ w9,
                                                         const float* __restrict__ s1, const float* __restrict__ t1,
                                                         float* __restrict__ out) {
    int gid = blockIdx.x;
    int row = gid & 63; int bc = gid >> 6; int c = bc & 255;
    int x = threadIdx.x;
    const float* base = y + (long)bc * 4096;
    float acc = 0.f;
    #pragma unroll
    for (int ky = 0; ky < 3; ky++) {
        int yy = row + ky - 1;
        if (yy < 0 || yy >= 64) continue;
        #pragma unroll
        for (int kx = 0; kx < 3; kx++) {
            int xx = x + kx - 1;
            if (xx < 0 || xx >= 64) continue;
            acc += base[yy * 64 + xx] * w9[c * 9 + ky * 3 + kx];
        }
    }
    out[(long)gid * 64 + x] = relu6(acc * s1[c] + t1[c]);
}

// ---------------- launch ----------------
extern "C" void kernel_launch(void* const* d_in, const int* in_sizes, int n_in,
                              void* d_out, int out_size, void* d_ws, size_t ws_size,
                              hipStream_t stream) {
    if (ws_size < (size_t)WS_FLOATS * 4) return;

    const void* x      = d_in[0];
    const void* down_w = d_in[1];
    const void* down_b = d_in[2];
    const void* up_w   = d_in[3];
    const void* up_b   = d_in[4];
    const void* wqkv_c = d_in[5];
    const void* bqkv_c = d_in[6];
    const void* wqkv_f = d_in[7];
    const void* bqkv_f = d_in[8];
    const void* dw_w   = d_in[9];
    const void* bn1_g  = d_in[10];
    const void* bn1_b  = d_in[11];
    const void* bn1_m  = d_in[12];
    const void* bn1_v  = d_in[13];
    const void* pw_w   = d_in[14];
    const void* bn2_g  = d_in[15];
    const void* bn2_b  = d_in[16];
    const void* bn2_m  = d_in[17];
    const void* bn2_v  = d_in[18];

    float* ws = (float*)d_ws;
    int* flagp = (int*)(ws + OFF_FLAG);
    dim3 blk(256);

    // fail-safe dtype flag: default 0 (fp32); detector sets 1 only on strong bf16 evidence
    hipMemsetAsync(flagp, 0, sizeof(int), stream);
    detect_kernel<<<1, blk, 0, stream>>>(x, flagp);

    cvt_kernel<<<32768, blk, 0, stream>>>(x, ws + OFF_XF, 8388608, flagp);
    cvt_kernel<<<4096, blk, 0, stream>>>(down_w, ws + OFF_DOWNW, 1048576, flagp);
    cvt_kernel<<<1, blk, 0, stream>>>(down_b, ws + OFF_DOWNB, 256, flagp);
    cvt_kernel<<<1, blk, 0, stream>>>(up_b, ws + OFF_UPB, 256, flagp);
    cvt_kernel<<<1, blk, 0, stream>>>(bqkv_c, ws + OFF_BQKVC, 192, flagp);
    cvt_kernel<<<1, blk, 0, stream>>>(bqkv_f, ws + OFF_BQKVF, 192, flagp);
    cvt_kernel<<<256, blk, 0, stream>>>(pw_w, ws + OFF_PWW, 65536, flagp);
    cvt_kernel<<<9, blk, 0, stream>>>(dw_w, ws + OFF_DWW, 2304, flagp);
    tqkv_kernel<<<48, blk, 0, stream>>>(wqkv_c, ws + OFF_WQKVC, flagp);
    tqkv_kernel<<<48, blk, 0, stream>>>(wqkv_f, ws + OFF_WQKVF, flagp);
    prep_up_kernel<<<4096, blk, 0, stream>>>(up_w, ws + OFF_UPW4, flagp);
    bn_prep_kernel<<<1, blk, 0, stream>>>(bn1_g, bn1_b, bn1_m, bn1_v, ws + OFF_BN1S, ws + OFF_BN1T, flagp);
    bn_prep_kernel<<<1, blk, 0, stream>>>(bn2_g, bn2_b, bn2_m, bn2_v, ws + OFF_BN2S, ws + OFF_BN2T, flagp);

    // down conv (implicit im2col from fp32 XF): M=8192, N=256, K=4096 -> xd NHWC
    gemm_k<1, 1><<<dim3(4, 128, 1), blk, 0, stream>>>(ws + OFF_XF, ws + OFF_DOWNW, ws + OFF_XDHWC,
        4096, 0, 0, 0, 0, 4096, ws + OFF_DOWNB, nullptr, nullptr, nullptr, nullptr, flagp);

    // coarse qkv: M=32768, N=192, K=64 -> Q, K, V [bh][tok][d]
    gemm_k<2, 0><<<dim3(3, 512, 1), blk, 0, stream>>>(ws + OFF_XDHWC, ws + OFF_WQKVC, ws + OFF_Q,
        64, 0, 0, 64, 1, 64, ws + OFF_BQKVC, nullptr, ws + OFF_KK, ws + OFF_V, nullptr, flagp);

    // coarse fused attention (+ colsums) -> OUTC, PSC
    attn_kernel<true><<<dim3(16, 32), blk, 0, stream>>>(ws + OFF_Q, ws + OFF_KK, ws + OFF_V,
        ws + OFF_OUTC, ws + OFF_PSC);
    score_reduce_kernel<<<128, blk, 0, stream>>>(ws + OFF_PSC, ws + OFF_SCORE);
    topk_kernel<<<32, blk, 0, stream>>>(ws + OFF_SCORE, (int*)(ws + OFF_TOPK));

    // up conv (transposed, implicit im2col, z=cls): M=8192, N=256, K=1024 -> coarse NCHW
    gemm_k<4, 2><<<dim3(4, 128, 4), blk, 0, stream>>>(ws + OFF_OUTC, ws + OFF_UPW4, ws + OFF_COARSE,
        1024, 0, 262144, 0, 0, 1024, ws + OFF_UPB, nullptr, nullptr, nullptr, nullptr, flagp);

    // fine attention
    gather_tokf_kernel<<<8192, blk, 0, stream>>>(ws + OFF_COARSE, (const int*)(ws + OFF_TOPK), ws + OFF_XDHWC);
    gemm_k<3, 0><<<dim3(3, 512, 1), blk, 0, stream>>>(ws + OFF_XDHWC, ws + OFF_WQKVF, ws + OFF_Q,
        64, 0, 0, 64, 1, 64, ws + OFF_BQKVF, nullptr, ws + OFF_KK, ws + OFF_V, nullptr, flagp);
    attn_kernel<false><<<dim3(16, 32), blk, 0, stream>>>(ws + OFF_Q, ws + OFF_KK, ws + OFF_V,
        ws + OFF_OUTC, nullptr);
    scatter_add_kernel<<<8192, blk, 0, stream>>>(ws + OFF_COARSE, (const int*)(ws + OFF_TOPK), ws + OFF_OUTC);

    // depthwise + bn1 + relu6 -> T1
    dw_bn_relu6_kernel<<<131072, dim3(64), 0, stream>>>(ws + OFF_COARSE, ws + OFF_DWW,
        ws + OFF_BN1S, ws + OFF_BN1T, ws + OFF_T1);

    // pointwise + bn2 + relu6 -> d_out (dtype per flag): z=8, M=4096, N=256, K=256
    gemm_k<5, 0><<<dim3(4, 64, 8), blk, 0, stream>>>(ws + OFF_T1, ws + OFF_PWW, nullptr,
        256, 1048576, 0, 1, 4096, 256, ws + OFF_BN2S, ws + OFF_BN2T, nullptr, nullptr, d_out, flagp);
}

// Round 7
// 1766.170 us; speedup vs baseline: 1.1152x; 1.1152x over previous
//
#include <hip/hip_runtime.h>
#include <hip/hip_bf16.h>

typedef __hip_bfloat16 bf16;

// B=8, C=256, H=W=64, nh=4, HD=64, coarse tokens N=1024 (32x32), kf=256, fine tokens 1024.
// fp32 inputs/outputs (auto-detected; bf16 path kept as insurance).

// ---------------- workspace layout (float offsets), peak 86.5 MB ----------------
#define OFF_XDHWC    0L
#define OFF_Q        2097152L
#define OFF_KK       4194304L
#define OFF_V        6291456L
#define OFF_T1       0L           // overlay on trunk (XDHWC/Q/K/V dead)
#define OFF_OUTC     8388608L
#define OFF_COARSE   10485760L    // xf (fp32 x) first, then coarse NCHW -> y
#define OFF_XF       10485760L
#define OFF_PSC      18874368L
#define OFF_SCORE    19398656L
#define OFF_TOPK     19431424L
#define OFF_DOWNW    19439616L
#define OFF_UPW4     20488192L
#define OFF_WQKVC    21536768L
#define OFF_BQKVC    21549056L
#define OFF_WQKVF    21549248L
#define OFF_BQKVF    21561536L
#define OFF_PWW      21561728L
#define OFF_DWW      21627264L
#define OFF_BN1S     21629568L
#define OFF_BN1T     21629824L
#define OFF_BN2S     21630080L
#define OFF_BN2T     21630336L
#define OFF_DOWNB    21630592L
#define OFF_UPB      21630848L
#define OFF_FLAG     21631104L    // 1 int: 1 = bf16 world, 0 = fp32 world (default via memset)
#define WS_FLOATS    21631360L

__device__ __forceinline__ float relu6(float v) { return v < 0.f ? 0.f : (v > 6.f ? 6.f : v); }

__device__ __forceinline__ float ldin(const void* p, long i, int flag) {
    return flag ? __bfloat162float(((const bf16*)p)[i]) : ((const float*)p)[i];
}

// ---------------- dtype detector ----------------
__global__ __launch_bounds__(256) void detect_kernel(const void* __restrict__ x, int* __restrict__ flag) {
    __shared__ int cnt[256];
    int tid = threadIdx.x;
    int c = 0;
    for (int i = tid; i < 4096; i += 256) {
        long idx = (long)i * 2047;
        float v = __bfloat162float(((const bf16*)x)[idx]);
        float a = fabsf(v);
        if (isfinite(v) && a > 1e-8f && a < 100.f) c++;
    }
    cnt[tid] = c; __syncthreads();
    for (int s = 128; s > 0; s >>= 1) { if (tid < s) cnt[tid] += cnt[tid + s]; __syncthreads(); }
    if (tid == 0 && cnt[0] >= 3686) *flag = 1;
}

// ---------------- prep kernels (dual-dtype) ----------------
__global__ __launch_bounds__(256) void cvt_kernel(const void* __restrict__ in, float* __restrict__ out,
                                                  int n, const int* __restrict__ flagp) {
    int flag = *flagp;
    int i = blockIdx.x * 256 + threadIdx.x;
    if (i < n) out[i] = ldin(in, i, flag);
}

__global__ __launch_bounds__(256) void tqkv_kernel(const void* __restrict__ w, float* __restrict__ wt,
                                                   const int* __restrict__ flagp) {
    int flag = *flagp;
    int idx = blockIdx.x * 256 + threadIdx.x;
    if (idx >= 192 * 64) return;
    int j = idx >> 6, d = idx & 63;
    wt[idx] = ldin(w, d * 192 + j, flag);
}

// up_w [ci,co,4,4] -> W4 [cls][co][ci*4+j]
// parity a=0: jy=0->(ky=1,dy=0), jy=1->(ky=3,dy=-1); a=1: jy=0->(ky=2,dy=0), jy=1->(ky=0,dy=+1)
__global__ __launch_bounds__(256) void prep_up_kernel(const void* __restrict__ w, float* __restrict__ W4,
                                                      const int* __restrict__ flagp) {
    int flag = *flagp;
    int idx = blockIdx.x * 256 + threadIdx.x;
    int cls = idx >> 18; int rem = idx & 262143;
    int co = rem >> 10; int q = rem & 1023;
    int ci = q >> 2; int j = q & 3;
    int pa = cls >> 1, pb = cls & 1;
    int jy = j >> 1, jx = j & 1;
    int ky = (pa == 0) ? (jy ? 3 : 1) : (jy ? 0 : 2);
    int kx = (pb == 0) ? (jx ? 3 : 1) : (jx ? 0 : 2);
    W4[idx] = ldin(w, (((long)ci * 256 + co) * 4 + ky) * 4 + kx, flag);
}

__global__ void bn_prep_kernel(const void* __restrict__ g, const void* __restrict__ b,
                               const void* __restrict__ m, const void* __restrict__ v,
                               float* __restrict__ s, float* __restrict__ t,
                               const int* __restrict__ flagp) {
    int flag = *flagp;
    int c = threadIdx.x;
    float gv = ldin(g, c, flag), bv = ldin(b, c, flag);
    float mv = ldin(m, c, flag), vv = ldin(v, c, flag);
    float inv = gv / sqrtf(vv + 1e-5f);
    s[c] = inv; t[c] = bv - mv * inv;
}

// ---------------- generic GEMM: C[m,n] = sum_k A[m,k]*B[n,k]; B k-contiguous ----------------
// LDS tiles padded to stride 68: staging-write bank = (kl*4+ml)%32 -> <=2-way (free).
// B staging (and A when sAk==1): float4 global load + 4 scalar LDS writes.
template<int EPI, int AMODE>
__global__ __launch_bounds__(256) void gemm_k(
    const float* __restrict__ A, const float* __restrict__ B, float* __restrict__ C,
    int K, long sAz, long sBz, int sAm, int sAk, int sBn,
    const float* __restrict__ e0, const float* __restrict__ e1,
    float* __restrict__ o1, float* __restrict__ o2, void* __restrict__ ob,
    const int* __restrict__ flagp)
{
    __shared__ float As[16][68];
    __shared__ float Bs[16][68];
    int z = blockIdx.z;
    if (AMODE == 0) A += (long)z * sAz;
    B += (long)z * sBz;
    int m0 = blockIdx.y * 64;
    int n0 = blockIdx.x * 64;
    int tid = threadIdx.x;
    int tx = tid & 15, ty = tid >> 4;
    int l4 = tid >> 2, kq = (tid & 3) * 4;   // float4 staging coords
    float acc[4][4] = {};
    for (int k0 = 0; k0 < K; k0 += 16) {
        if (AMODE == 0) {
            if (sAk == 1) {
                float4 v4 = *(const float4*)(A + (long)(m0 + l4) * sAm + (k0 + kq));
                As[kq + 0][l4] = v4.x;
                As[kq + 1][l4] = v4.y;
                As[kq + 2][l4] = v4.z;
                As[kq + 3][l4] = v4.w;
            } else {
                for (int i = tid; i < 1024; i += 256) {
                    int ml = i & 63, kl = i >> 6;
                    As[kl][ml] = A[(long)(m0 + ml) * sAm + (long)(k0 + kl) * sAk];
                }
            }
        } else if (AMODE == 1) {  // xf[b,c,iy,ix], m=(b,oy,ox), k=(c,ky,kx)
            for (int i = tid; i < 1024; i += 256) {
                int kl = i & 15, ml = i >> 4;
                int m = m0 + ml, k = k0 + kl;
                int b = m >> 10, oy = (m >> 5) & 31, ox = m & 31;
                int c = k >> 4, ky = (k >> 2) & 3, kx = k & 3;
                int iy = 2 * oy - 1 + ky, ix = 2 * ox - 1 + kx;
                float val = 0.f;
                if ((unsigned)iy < 64u && (unsigned)ix < 64u)
                    val = A[(((long)b * 256 + c) * 64 + iy) * 64 + ix];
                As[kl][ml] = val;
            }
        } else {  // AMODE 2: OUTC[bh,tok,d], m=(b,y,x), k=(ci,j), cls=z
            for (int i = tid; i < 1024; i += 256) {
                int kl = i & 15, ml = i >> 4;
                int m = m0 + ml, k = k0 + kl;
                int b = m >> 10, y = (m >> 5) & 31, x2 = m & 31;
                int ci = k >> 2, j = k & 3;
                int pa = z >> 1, pb = z & 1;
                int jy = j >> 1, jx = j & 1;
                int dy = (pa == 0) ? (jy ? -1 : 0) : (jy ? 1 : 0);
                int dx = (pb == 0) ? (jx ? -1 : 0) : (jx ? 1 : 0);
                int yy = y + dy, xx = x2 + dx;
                float val = 0.f;
                if ((unsigned)yy < 32u && (unsigned)xx < 32u)
                    val = A[(((long)b * 4 + (ci >> 6)) * 1024 + yy * 32 + xx) * 64 + (ci & 63)];
                As[kl][ml] = val;
            }
        }
        {   // B staging: always k-contiguous
            float4 v4 = *(const float4*)(B + (long)(n0 + l4) * sBn + (k0 + kq));
            Bs[kq + 0][l4] = v4.x;
            Bs[kq + 1][l4] = v4.y;
            Bs[kq + 2][l4] = v4.z;
            Bs[kq + 3][l4] = v4.w;
        }
        __syncthreads();
        #pragma unroll
        for (int kk = 0; kk < 16; ++kk) {
            float4 av = *reinterpret_cast<const float4*>(&As[kk][ty * 4]);
            float4 bv = *reinterpret_cast<const float4*>(&Bs[kk][tx * 4]);
            float a[4] = {av.x, av.y, av.z, av.w};
            float b[4] = {bv.x, bv.y, bv.z, bv.w};
            #pragma unroll
            for (int i = 0; i < 4; i++)
                #pragma unroll
                for (int j = 0; j < 4; j++)
                    acc[i][j] += a[i] * b[j];
        }
        __syncthreads();
    }
    int oflag = (EPI == 5) ? *flagp : 0;
    #pragma unroll
    for (int i = 0; i < 4; i++) {
        int m = m0 + ty * 4 + i;
        #pragma unroll
        for (int j = 0; j < 4; j++) {
            int n = n0 + tx * 4 + j;
            float v = acc[i][j];
            if (EPI == 1) {
                C[(long)m * 256 + n] = v + e0[n];
            } else if (EPI == 2 || EPI == 3) {
                v += e0[n];
                int bh, tok;
                if (EPI == 2) { int bi = m >> 12; int h = m & 3; tok = (m >> 2) & 1023; bh = bi * 4 + h; }
                else          { bh = m >> 10; tok = m & 1023; }
                long base = ((long)bh * 1024 + tok) * 64;
                if (n < 64) C[base + n] = v;
                else if (n < 128) o1[base + (n - 64)] = v;
                else o2[base + (n - 128)] = v;
            } else if (EPI == 4) {
                v += e0[n];
                int pa = z >> 1, pb = z & 1;
                int bi = m >> 10, y = (m >> 5) & 31, x2 = m & 31;
                C[(((long)bi * 256 + n) * 64 + (2 * y + pa)) * 64 + (2 * x2 + pb)] = v;
            } else if (EPI == 5) {
                v = relu6(v * e0[n] + e1[n]);
                long oidx = (long)z * 1048576 + (long)n * 4096 + m;
                if (oflag) ((bf16*)ob)[oidx] = __float2bfloat16(v);
                else       ((float*)ob)[oidx] = v;
            }
        }
    }
}

// ---------------- fused two-pass attention: [bh=32][N=1024][D=64], scale 1/8 folded into Q ----------------
template<bool SCORE>
__global__ __launch_bounds__(256) void attn_kernel(
    const float* __restrict__ Q, const float* __restrict__ K, const float* __restrict__ V,
    float* __restrict__ O, float* __restrict__ PSC)
{
    __shared__ __align__(16) float QT[64 * 68];
    __shared__ __align__(16) float KV[64 * 68];
    __shared__ __align__(16) float Ps[64 * 68];
    __shared__ float colpart[16 * 64];
    int bh = blockIdx.y, rt = blockIdx.x;
    int tid = threadIdx.x;
    int tx = tid & 15, ty = tid >> 4;
    long qbase = ((long)bh * 1024 + rt * 64) * 64;
    for (int q = tid; q < 1024; q += 256) {
        int r = q >> 4, d4 = (q & 15) * 4;
        float4 v4 = *(const float4*)(Q + qbase + r * 64 + d4);
        QT[(d4 + 0) * 68 + r] = v4.x * 0.125f;
        QT[(d4 + 1) * 68 + r] = v4.y * 0.125f;
        QT[(d4 + 2) * 68 + r] = v4.z * 0.125f;
        QT[(d4 + 3) * 68 + r] = v4.w * 0.125f;
    }
    float m[4], l[4];
    #pragma unroll
    for (int i = 0; i < 4; i++) { m[i] = -1e30f; l[i] = 0.f; }
    __syncthreads();

    for (int t = 0; t < 16; ++t) {   // pass 1: row max + sumexp
        long kbase = ((long)bh * 1024 + t * 64) * 64;
        for (int q = tid; q < 1024; q += 256) {
            int c = q >> 4, d4 = (q & 15) * 4;
            float4 v4 = *(const float4*)(K + kbase + c * 64 + d4);
            KV[(d4 + 0) * 68 + c] = v4.x;
            KV[(d4 + 1) * 68 + c] = v4.y;
            KV[(d4 + 2) * 68 + c] = v4.z;
            KV[(d4 + 3) * 68 + c] = v4.w;
        }
        __syncthreads();
        float zv[4][4] = {};
        for (int d = 0; d < 64; ++d) {
            float4 qa = *(const float4*)(QT + d * 68 + ty * 4);
            float4 kb = *(const float4*)(KV + d * 68 + tx * 4);
            float a[4] = {qa.x, qa.y, qa.z, qa.w};
            float b[4] = {kb.x, kb.y, kb.z, kb.w};
            #pragma unroll
            for (int i = 0; i < 4; i++)
                #pragma unroll
                for (int j = 0; j < 4; j++)
                    zv[i][j] += a[i] * b[j];
        }
        #pragma unroll
        for (int i = 0; i < 4; i++) {
            float tm = fmaxf(fmaxf(zv[i][0], zv[i][1]), fmaxf(zv[i][2], zv[i][3]));
            for (int off = 1; off < 16; off <<= 1) tm = fmaxf(tm, __shfl_xor(tm, off, 16));
            float mn = fmaxf(m[i], tm);
            float ss = __expf(zv[i][0] - mn) + __expf(zv[i][1] - mn) + __expf(zv[i][2] - mn) + __expf(zv[i][3] - mn);
            for (int off = 1; off < 16; off <<= 1) ss += __shfl_xor(ss, off, 16);
            l[i] = l[i] * __expf(m[i] - mn) + ss;
            m[i] = mn;
        }
        __syncthreads();
    }
    float linv[4];
    #pragma unroll
    for (int i = 0; i < 4; i++) linv[i] = 1.f / l[i];

    float Oa[4][4] = {};
    for (int t = 0; t < 16; ++t) {   // pass 2: exact probs, O=P@V, colsums
        long kbase = ((long)bh * 1024 + t * 64) * 64;
        for (int q = tid; q < 1024; q += 256) {
            int c = q >> 4, d4 = (q & 15) * 4;
            float4 v4 = *(const float4*)(K + kbase + c * 64 + d4);
            KV[(d4 + 0) * 68 + c] = v4.x;
            KV[(d4 + 1) * 68 + c] = v4.y;
            KV[(d4 + 2) * 68 + c] = v4.z;
            KV[(d4 + 3) * 68 + c] = v4.w;
        }
        __syncthreads();
        float zv[4][4] = {};
        for (int d = 0; d < 64; ++d) {
            float4 qa = *(const float4*)(QT + d * 68 + ty * 4);
            float4 kb = *(const float4*)(KV + d * 68 + tx * 4);
            float a[4] = {qa.x, qa.y, qa.z, qa.w};
            float b[4] = {kb.x, kb.y, kb.z, kb.w};
            #pragma unroll
            for (int i = 0; i < 4; i++)
                #pragma unroll
                for (int j = 0; j < 4; j++)
                    zv[i][j] += a[i] * b[j];
        }
        float cs[4] = {0.f, 0.f, 0.f, 0.f};
        #pragma unroll
        for (int i = 0; i < 4; i++)
            #pragma unroll
            for (int j = 0; j < 4; j++) {
                float p = __expf(zv[i][j] - m[i]) * linv[i];
                Ps[(ty * 4 + i) * 68 + tx * 4 + j] = p;
                cs[j] += p;
            }
        if (SCORE) {
            #pragma unroll
            for (int j = 0; j < 4; j++) colpart[ty * 64 + tx * 4 + j] = cs[j];
        }
        __syncthreads();
        if (SCORE && tid < 64) {
            float s = 0.f;
            #pragma unroll
            for (int g = 0; g < 16; g++) s += colpart[g * 64 + tid];
            PSC[((long)(bh * 16 + rt) << 10) + t * 64 + tid] = s;
        }
        for (int q = tid; q < 1024; q += 256) {
            int c = q >> 4, d4 = (q & 15) * 4;
            float4 v4 = *(const float4*)(V + kbase + c * 64 + d4);
            *(float4*)(KV + c * 68 + d4) = v4;
        }
        __syncthreads();
        for (int c = 0; c < 64; ++c) {
            float4 vb = *(const float4*)(KV + c * 68 + tx * 4);
            float b[4] = {vb.x, vb.y, vb.z, vb.w};
            float pv[4];
            #pragma unroll
            for (int i = 0; i < 4; i++) pv[i] = Ps[(ty * 4 + i) * 68 + c];
            #pragma unroll
            for (int i = 0; i < 4; i++)
                #pragma unroll
                for (int j = 0; j < 4; j++)
                    Oa[i][j] += pv[i] * b[j];
        }
        __syncthreads();
    }
    #pragma unroll
    for (int i = 0; i < 4; i++) {
        float4 o4 = make_float4(Oa[i][0], Oa[i][1], Oa[i][2], Oa[i][3]);
        *(float4*)(O + qbase + (ty * 4 + i) * 64 + tx * 4) = o4;
    }
}

__global__ __launch_bounds__(256) void score_reduce_kernel(const float* __restrict__ PSC, float* __restrict__ score) {
    int idx = blockIdx.x * 256 + threadIdx.x;
    int bh = idx >> 10, c = idx & 1023;
    float s = 0.f;
    for (int rt = 0; rt < 16; rt++) s += PSC[((long)(bh * 16 + rt) << 10) + c];
    score[idx] = s;
}

__global__ __launch_bounds__(256) void topk_kernel(const float* __restrict__ score, int* __restrict__ topk) {
    __shared__ float s[1024];
    int z = blockIdx.x; int tid = threadIdx.x;
    for (int i = tid; i < 1024; i += 256) {
        float v = score[z * 1024 + i];
        s[i] = (v == v) ? v : -INFINITY;
    }
    __syncthreads();
    for (int i = tid; i < 1024; i += 256) {
        float si = s[i]; int r = 0;
        for (int j = 0; j < 1024; j++) {
            float sj = s[j];
            r += (sj > si) || (sj == si && j < i);
        }
        if (r < 256) topk[z * 256 + r] = i;
    }
}

__global__ __launch_bounds__(256) void gather_tokf_kernel(const float* __restrict__ coarse,
                                                          const int* __restrict__ topk,
                                                          float* __restrict__ tokf) {
    long idx = (long)blockIdx.x * 256 + threadIdx.x;
    int d = (int)(idx & 63); int t = (int)((idx >> 6) & 3);
    int j = (int)((idx >> 8) & 255); int bh = (int)(idx >> 16);
    int p = topk[bh * 256 + j] & 1023;
    int py = p >> 5, px = p & 31;
    int dy = t >> 1, dx = t & 1;
    int b = bh >> 2, h = bh & 3;
    tokf[idx] = coarse[(((long)b * 256 + h * 64 + d) * 64 + (2 * py + dy)) * 64 + (2 * px + dx)];
}

__global__ __launch_bounds__(256) void scatter_add_kernel(float* __restrict__ coarse,
                                                          const int* __restrict__ topk,
                                                          const float* __restrict__ outf) {
    long idx = (long)blockIdx.x * 256 + threadIdx.x;
    int d = (int)(idx & 63); int t = (int)((idx >> 6) & 3);
    int j = (int)((idx >> 8) & 255); int bh = (int)(idx >> 16);
    int p = topk[bh * 256 + j] & 1023;
    int py = p >> 5, px = p & 31;
    int dy = t >> 1, dx = t & 1;
    int b = bh >> 2, h = bh & 3;
    coarse[(((long)b * 256 + h * 64 + d) * 64 + (2 * py + dy)) * 64 + (2 * px + dx)] += outf[idx];
}

__global__ __launch_bounds__(64) void dw_bn_relu6_kernel(const float* __restrict__ y, const float* __restrict__ w9,
                                                         const float* __restrict__ s1, const float* __restrict__ t1,
                                                         float* __restrict__ out) {
    int gid = blockIdx.x;
    int row = gid & 63; int bc = gid >> 6; int c = bc & 255;
    int x = threadIdx.x;
    const float* base = y + (long)bc * 4096;
    float acc = 0.f;
    #pragma unroll
    for (int ky = 0; ky < 3; ky++) {
        int yy = row + ky - 1;
        if (yy < 0 || yy >= 64) continue;
        #pragma unroll
        for (int kx = 0; kx < 3; kx++) {
            int xx = x + kx - 1;
            if (xx < 0 || xx >= 64) continue;
            acc += base[yy * 64 + xx] * w9[c * 9 + ky * 3 + kx];
        }
    }
    out[(long)gid * 64 + x] = relu6(acc * s1[c] + t1[c]);
}

// ---------------- launch ----------------
extern "C" void kernel_launch(void* const* d_in, const int* in_sizes, int n_in,
                              void* d_out, int out_size, void* d_ws, size_t ws_size,
                              hipStream_t stream) {
    if (ws_size < (size_t)WS_FLOATS * 4) return;

    const void* x      = d_in[0];
    const void* down_w = d_in[1];
    const void* down_b = d_in[2];
    const void* up_w   = d_in[3];
    const void* up_b   = d_in[4];
    const void* wqkv_c = d_in[5];
    const void* bqkv_c = d_in[6];
    const void* wqkv_f = d_in[7];
    const void* bqkv_f = d_in[8];
    const void* dw_w   = d_in[9];
    const void* bn1_g  = d_in[10];
    const void* bn1_b  = d_in[11];
    const void* bn1_m  = d_in[12];
    const void* bn1_v  = d_in[13];
    const void* pw_w   = d_in[14];
    const void* bn2_g  = d_in[15];
    const void* bn2_b  = d_in[16];
    const void* bn2_m  = d_in[17];
    const void* bn2_v  = d_in[18];

    float* ws = (float*)d_ws;
    int* flagp = (int*)(ws + OFF_FLAG);
    dim3 blk(256);

    hipMemsetAsync(flagp, 0, sizeof(int), stream);
    detect_kernel<<<1, blk, 0, stream>>>(x, flagp);

    cvt_kernel<<<32768, blk, 0, stream>>>(x, ws + OFF_XF, 8388608, flagp);
    cvt_kernel<<<4096, blk, 0, stream>>>(down_w, ws + OFF_DOWNW, 1048576, flagp);
    cvt_kernel<<<1, blk, 0, stream>>>(down_b, ws + OFF_DOWNB, 256, flagp);
    cvt_kernel<<<1, blk, 0, stream>>>(up_b, ws + OFF_UPB, 256, flagp);
    cvt_kernel<<<1, blk, 0, stream>>>(bqkv_c, ws + OFF_BQKVC, 192, flagp);
    cvt_kernel<<<1, blk, 0, stream>>>(bqkv_f, ws + OFF_BQKVF, 192, flagp);
    cvt_kernel<<<256, blk, 0, stream>>>(pw_w, ws + OFF_PWW, 65536, flagp);
    cvt_kernel<<<9, blk, 0, stream>>>(dw_w, ws + OFF_DWW, 2304, flagp);
    tqkv_kernel<<<48, blk, 0, stream>>>(wqkv_c, ws + OFF_WQKVC, flagp);
    tqkv_kernel<<<48, blk, 0, stream>>>(wqkv_f, ws + OFF_WQKVF, flagp);
    prep_up_kernel<<<4096, blk, 0, stream>>>(up_w, ws + OFF_UPW4, flagp);
    bn_prep_kernel<<<1, blk, 0, stream>>>(bn1_g, bn1_b, bn1_m, bn1_v, ws + OFF_BN1S, ws + OFF_BN1T, flagp);
    bn_prep_kernel<<<1, blk, 0, stream>>>(bn2_g, bn2_b, bn2_m, bn2_v, ws + OFF_BN2S, ws + OFF_BN2T, flagp);

    // down conv (implicit im2col from fp32 XF): M=8192, N=256, K=4096 -> xd NHWC
    gemm_k<1, 1><<<dim3(4, 128, 1), blk, 0, stream>>>(ws + OFF_XF, ws + OFF_DOWNW, ws + OFF_XDHWC,
        4096, 0, 0, 0, 0, 4096, ws + OFF_DOWNB, nullptr, nullptr, nullptr, nullptr, flagp);

    // coarse qkv: M=32768, N=192, K=64 -> Q, K, V [bh][tok][d]
    gemm_k<2, 0><<<dim3(3, 512, 1), blk, 0, stream>>>(ws + OFF_XDHWC, ws + OFF_WQKVC, ws + OFF_Q,
        64, 0, 0, 64, 1, 64, ws + OFF_BQKVC, nullptr, ws + OFF_KK, ws + OFF_V, nullptr, flagp);

    // coarse fused attention (+ colsums) -> OUTC, PSC
    attn_kernel<true><<<dim3(16, 32), blk, 0, stream>>>(ws + OFF_Q, ws + OFF_KK, ws + OFF_V,
        ws + OFF_OUTC, ws + OFF_PSC);
    score_reduce_kernel<<<128, blk, 0, stream>>>(ws + OFF_PSC, ws + OFF_SCORE);
    topk_kernel<<<32, blk, 0, stream>>>(ws + OFF_SCORE, (int*)(ws + OFF_TOPK));

    // up conv (transposed, implicit im2col, z=cls): M=8192, N=256, K=1024 -> coarse NCHW
    gemm_k<4, 2><<<dim3(4, 128, 4), blk, 0, stream>>>(ws + OFF_OUTC, ws + OFF_UPW4, ws + OFF_COARSE,
        1024, 0, 262144, 0, 0, 1024, ws + OFF_UPB, nullptr, nullptr, nullptr, nullptr, flagp);

    // fine attention
    gather_tokf_kernel<<<8192, blk, 0, stream>>>(ws + OFF_COARSE, (const int*)(ws + OFF_TOPK), ws + OFF_XDHWC);
    gemm_k<3, 0><<<dim3(3, 512, 1), blk, 0, stream>>>(ws + OFF_XDHWC, ws + OFF_WQKVF, ws + OFF_Q,
        64, 0, 0, 64, 1, 64, ws + OFF_BQKVF, nullptr, ws + OFF_KK, ws + OFF_V, nullptr, flagp);
    attn_kernel<false><<<dim3(16, 32), blk, 0, stream>>>(ws + OFF_Q, ws + OFF_KK, ws + OFF_V,
        ws + OFF_OUTC, nullptr);
    scatter_add_kernel<<<8192, blk, 0, stream>>>(ws + OFF_COARSE, (const int*)(ws + OFF_TOPK), ws + OFF_OUTC);

    // depthwise + bn1 + relu6 -> T1
    dw_bn_relu6_kernel<<<131072, dim3(64), 0, stream>>>(ws + OFF_COARSE, ws + OFF_DWW,
        ws + OFF_BN1S, ws + OFF_BN1T, ws + OFF_T1);

    // pointwise + bn2 + relu6 -> d_out (dtype per flag): z=8, M=4096, N=256, K=256
    gemm_k<5, 0><<<dim3(4, 64, 8), blk, 0, stream>>>(ws + OFF_T1, ws + OFF_PWW, nullptr,
        256, 1048576, 0, 1, 4096, 256, ws + OFF_BN2S, ws + OFF_BN2T, nullptr, nullptr, d_out, flagp);
}

// Round 8
// 1433.306 us; speedup vs baseline: 1.3741x; 1.2322x over previous
//
#include <hip/hip_runtime.h>
#include <hip/hip_bf16.h>

typedef __hip_bfloat16 bf16;

// B=8, C=256, H=W=64, nh=4, HD=64, coarse tokens N=1024 (32x32), kf=256, fine tokens 1024.
// fp32 inputs/outputs (auto-detected; bf16 path kept as insurance).

// ---------------- workspace layout (float offsets), peak 86.5 MB ----------------
#define OFF_XDHWC    0L
#define OFF_Q        2097152L
#define OFF_KK       4194304L
#define OFF_V        6291456L
#define OFF_T1       0L           // overlay on trunk (XDHWC/Q/K/V dead)
#define OFF_OUTC     8388608L
#define OFF_COARSE   10485760L    // xf (fp32 x) first, then coarse NCHW -> y
#define OFF_XF       10485760L
#define OFF_PSC      18874368L
#define OFF_SCORE    19398656L
#define OFF_TOPK     19431424L
#define OFF_DOWNW    19439616L
#define OFF_UPW4     20488192L
#define OFF_WQKVC    21536768L
#define OFF_BQKVC    21549056L
#define OFF_WQKVF    21549248L
#define OFF_BQKVF    21561536L
#define OFF_PWW      21561728L
#define OFF_DWW      21627264L
#define OFF_BN1S     21629568L
#define OFF_BN1T     21629824L
#define OFF_BN2S     21630080L
#define OFF_BN2T     21630336L
#define OFF_DOWNB    21630592L
#define OFF_UPB      21630848L
#define OFF_FLAG     21631104L    // 1 int: 1 = bf16 world, 0 = fp32 world (default via memset)
#define WS_FLOATS    21631360L

__device__ __forceinline__ float relu6(float v) { return v < 0.f ? 0.f : (v > 6.f ? 6.f : v); }

__device__ __forceinline__ float ldin(const void* p, long i, int flag) {
    return flag ? __bfloat162float(((const bf16*)p)[i]) : ((const float*)p)[i];
}

// ---------------- dtype detector ----------------
__global__ __launch_bounds__(256) void detect_kernel(const void* __restrict__ x, int* __restrict__ flag) {
    __shared__ int cnt[256];
    int tid = threadIdx.x;
    int c = 0;
    for (int i = tid; i < 4096; i += 256) {
        long idx = (long)i * 2047;
        float v = __bfloat162float(((const bf16*)x)[idx]);
        float a = fabsf(v);
        if (isfinite(v) && a > 1e-8f && a < 100.f) c++;
    }
    cnt[tid] = c; __syncthreads();
    for (int s = 128; s > 0; s >>= 1) { if (tid < s) cnt[tid] += cnt[tid + s]; __syncthreads(); }
    if (tid == 0 && cnt[0] >= 3686) *flag = 1;
}

// ---------------- prep kernels (dual-dtype) ----------------
__global__ __launch_bounds__(256) void cvt_kernel(const void* __restrict__ in, float* __restrict__ out,
                                                  int n, const int* __restrict__ flagp) {
    int flag = *flagp;
    int i = blockIdx.x * 256 + threadIdx.x;
    if (i < n) out[i] = ldin(in, i, flag);
}

__global__ __launch_bounds__(256) void tqkv_kernel(const void* __restrict__ w, float* __restrict__ wt,
                                                   const int* __restrict__ flagp) {
    int flag = *flagp;
    int idx = blockIdx.x * 256 + threadIdx.x;
    if (idx >= 192 * 64) return;
    int j = idx >> 6, d = idx & 63;
    wt[idx] = ldin(w, d * 192 + j, flag);
}

// up_w [ci,co,4,4] -> W4 [cls][co][ci*4+j]
// parity a=0: jy=0->(ky=1,dy=0), jy=1->(ky=3,dy=-1); a=1: jy=0->(ky=2,dy=0), jy=1->(ky=0,dy=+1)
__global__ __launch_bounds__(256) void prep_up_kernel(const void* __restrict__ w, float* __restrict__ W4,
                                                      const int* __restrict__ flagp) {
    int flag = *flagp;
    int idx = blockIdx.x * 256 + threadIdx.x;
    int cls = idx >> 18; int rem = idx & 262143;
    int co = rem >> 10; int q = rem & 1023;
    int ci = q >> 2; int j = q & 3;
    int pa = cls >> 1, pb = cls & 1;
    int jy = j >> 1, jx = j & 1;
    int ky = (pa == 0) ? (jy ? 3 : 1) : (jy ? 0 : 2);
    int kx = (pb == 0) ? (jx ? 3 : 1) : (jx ? 0 : 2);
    W4[idx] = ldin(w, (((long)ci * 256 + co) * 4 + ky) * 4 + kx, flag);
}

__global__ void bn_prep_kernel(const void* __restrict__ g, const void* __restrict__ b,
                               const void* __restrict__ m, const void* __restrict__ v,
                               float* __restrict__ s, float* __restrict__ t,
                               const int* __restrict__ flagp) {
    int flag = *flagp;
    int c = threadIdx.x;
    float gv = ldin(g, c, flag), bv = ldin(b, c, flag);
    float mv = ldin(m, c, flag), vv = ldin(v, c, flag);
    float inv = gv / sqrtf(vv + 1e-5f);
    s[c] = inv; t[c] = bv - mv * inv;
}

// ---------------- generic GEMM: C[m,n] = sum_k A[m,k]*B[n,k]; B k-contiguous ----------------
// LDS stride 68 (<=2-way staging banks). Software-pipelined: tile k+1 register-prefetched
// right after the barrier so global loads overlap the FMA phase (G7/G15).
template<int EPI, int AMODE>
__global__ __launch_bounds__(256) void gemm_k(
    const float* __restrict__ A, const float* __restrict__ B, float* __restrict__ C,
    int K, long sAz, long sBz, int sAm, int sAk, int sBn,
    const float* __restrict__ e0, const float* __restrict__ e1,
    float* __restrict__ o1, float* __restrict__ o2, void* __restrict__ ob,
    const int* __restrict__ flagp)
{
    __shared__ float As[16][68];
    __shared__ float Bs[16][68];
    int z = blockIdx.z;
    if (AMODE == 0) A += (long)z * sAz;
    B += (long)z * sBz;
    int m0 = blockIdx.y * 64;
    int n0 = blockIdx.x * 64;
    int tid = threadIdx.x;
    int tx = tid & 15, ty = tid >> 4;
    int l4 = tid >> 2, kq = (tid & 3) * 4;   // float4 staging coords
    float aR[4];
    float4 bR;

    auto loadA = [&](int k0) {
        if (AMODE == 0) {
            if (sAk == 1) {
                float4 v4 = *(const float4*)(A + (long)(m0 + l4) * sAm + (k0 + kq));
                aR[0] = v4.x; aR[1] = v4.y; aR[2] = v4.z; aR[3] = v4.w;
            } else {
                #pragma unroll
                for (int i = 0; i < 4; i++) {
                    int idx = i * 256 + tid;
                    int ml = idx & 63, kl = idx >> 6;
                    aR[i] = A[(long)(m0 + ml) * sAm + (long)(k0 + kl) * sAk];
                }
            }
        } else if (AMODE == 1) {  // xf[b,c,iy,ix], m=(b,oy,ox), k=(c,ky,kx)
            #pragma unroll
            for (int i = 0; i < 4; i++) {
                int idx = i * 256 + tid;
                int kl = idx & 15, ml = idx >> 4;
                int m = m0 + ml, k = k0 + kl;
                int b = m >> 10, oy = (m >> 5) & 31, ox = m & 31;
                int c = k >> 4, ky = (k >> 2) & 3, kx = k & 3;
                int iy = 2 * oy - 1 + ky, ix = 2 * ox - 1 + kx;
                float val = 0.f;
                if ((unsigned)iy < 64u && (unsigned)ix < 64u)
                    val = A[(((long)b * 256 + c) * 64 + iy) * 64 + ix];
                aR[i] = val;
            }
        } else {  // AMODE 2: OUTC[bh,tok,d], m=(b,y,x), k=(ci,j), cls=z
            #pragma unroll
            for (int i = 0; i < 4; i++) {
                int idx = i * 256 + tid;
                int kl = idx & 15, ml = idx >> 4;
                int m = m0 + ml, k = k0 + kl;
                int b = m >> 10, y = (m >> 5) & 31, x2 = m & 31;
                int ci = k >> 2, j = k & 3;
                int pa = z >> 1, pb = z & 1;
                int jy = j >> 1, jx = j & 1;
                int dy = (pa == 0) ? (jy ? -1 : 0) : (jy ? 1 : 0);
                int dx = (pb == 0) ? (jx ? -1 : 0) : (jx ? 1 : 0);
                int yy = y + dy, xx = x2 + dx;
                float val = 0.f;
                if ((unsigned)yy < 32u && (unsigned)xx < 32u)
                    val = A[(((long)b * 4 + (ci >> 6)) * 1024 + yy * 32 + xx) * 64 + (ci & 63)];
                aR[i] = val;
            }
        }
    };
    auto storeA = [&]() {
        if (AMODE == 0 && sAk == 1) {
            As[kq + 0][l4] = aR[0];
            As[kq + 1][l4] = aR[1];
            As[kq + 2][l4] = aR[2];
            As[kq + 3][l4] = aR[3];
        } else if (AMODE == 0) {
            #pragma unroll
            for (int i = 0; i < 4; i++) {
                int idx = i * 256 + tid;
                int ml = idx & 63, kl = idx >> 6;
                As[kl][ml] = aR[i];
            }
        } else {
            #pragma unroll
            for (int i = 0; i < 4; i++) {
                int idx = i * 256 + tid;
                int kl = idx & 15, ml = idx >> 4;
                As[kl][ml] = aR[i];
            }
        }
    };
    auto loadB = [&](int k0) {
        bR = *(const float4*)(B + (long)(n0 + l4) * sBn + (k0 + kq));
    };

    float acc[4][4] = {};
    loadA(0); loadB(0);
    for (int k0 = 0; k0 < K; k0 += 16) {
        storeA();
        Bs[kq + 0][l4] = bR.x;
        Bs[kq + 1][l4] = bR.y;
        Bs[kq + 2][l4] = bR.z;
        Bs[kq + 3][l4] = bR.w;
        __syncthreads();
        if (k0 + 16 < K) { loadA(k0 + 16); loadB(k0 + 16); }   // in flight during compute
        #pragma unroll
        for (int kk = 0; kk < 16; ++kk) {
            float4 av = *reinterpret_cast<const float4*>(&As[kk][ty * 4]);
            float4 bv = *reinterpret_cast<const float4*>(&Bs[kk][tx * 4]);
            float a[4] = {av.x, av.y, av.z, av.w};
            float b[4] = {bv.x, bv.y, bv.z, bv.w};
            #pragma unroll
            for (int i = 0; i < 4; i++)
                #pragma unroll
                for (int j = 0; j < 4; j++)
                    acc[i][j] += a[i] * b[j];
        }
        __syncthreads();
    }
    int oflag = (EPI == 5) ? *flagp : 0;
    #pragma unroll
    for (int i = 0; i < 4; i++) {
        int m = m0 + ty * 4 + i;
        #pragma unroll
        for (int j = 0; j < 4; j++) {
            int n = n0 + tx * 4 + j;
            float v = acc[i][j];
            if (EPI == 1) {
                C[(long)m * 256 + n] = v + e0[n];
            } else if (EPI == 2 || EPI == 3) {
                v += e0[n];
                int bh, tok;
                if (EPI == 2) { int bi = m >> 12; int h = m & 3; tok = (m >> 2) & 1023; bh = bi * 4 + h; }
                else          { bh = m >> 10; tok = m & 1023; }
                long base = ((long)bh * 1024 + tok) * 64;
                if (n < 64) C[base + n] = v;
                else if (n < 128) o1[base + (n - 64)] = v;
                else o2[base + (n - 128)] = v;
            } else if (EPI == 4) {
                v += e0[n];
                int pa = z >> 1, pb = z & 1;
                int bi = m >> 10, y = (m >> 5) & 31, x2 = m & 31;
                C[(((long)bi * 256 + n) * 64 + (2 * y + pa)) * 64 + (2 * x2 + pb)] = v;
            } else if (EPI == 5) {
                v = relu6(v * e0[n] + e1[n]);
                long oidx = (long)z * 1048576 + (long)n * 4096 + m;
                if (oflag) ((bf16*)ob)[oidx] = __float2bfloat16(v);
                else       ((float*)ob)[oidx] = v;
            }
        }
    }
}

// ---------------- fused two-pass attention: [bh=32][N=1024][D=64], scale 1/8 folded into Q ----------------
template<bool SCORE>
__global__ __launch_bounds__(256) void attn_kernel(
    const float* __restrict__ Q, const float* __restrict__ K, const float* __restrict__ V,
    float* __restrict__ O, float* __restrict__ PSC)
{
    __shared__ __align__(16) float QT[64 * 68];
    __shared__ __align__(16) float KV[64 * 68];
    __shared__ __align__(16) float Ps[64 * 68];
    __shared__ float colpart[16 * 64];
    int bh = blockIdx.y, rt = blockIdx.x;
    int tid = threadIdx.x;
    int tx = tid & 15, ty = tid >> 4;
    long qbase = ((long)bh * 1024 + rt * 64) * 64;
    for (int q = tid; q < 1024; q += 256) {
        int r = q >> 4, d4 = (q & 15) * 4;
        float4 v4 = *(const float4*)(Q + qbase + r * 64 + d4);
        QT[(d4 + 0) * 68 + r] = v4.x * 0.125f;
        QT[(d4 + 1) * 68 + r] = v4.y * 0.125f;
        QT[(d4 + 2) * 68 + r] = v4.z * 0.125f;
        QT[(d4 + 3) * 68 + r] = v4.w * 0.125f;
    }
    float m[4], l[4];
    #pragma unroll
    for (int i = 0; i < 4; i++) { m[i] = -1e30f; l[i] = 0.f; }
    __syncthreads();

    for (int t = 0; t < 16; ++t) {   // pass 1: row max + sumexp
        long kbase = ((long)bh * 1024 + t * 64) * 64;
        for (int q = tid; q < 1024; q += 256) {
            int c = q >> 4, d4 = (q & 15) * 4;
            float4 v4 = *(const float4*)(K + kbase + c * 64 + d4);
            KV[(d4 + 0) * 68 + c] = v4.x;
            KV[(d4 + 1) * 68 + c] = v4.y;
            KV[(d4 + 2) * 68 + c] = v4.z;
            KV[(d4 + 3) * 68 + c] = v4.w;
        }
        __syncthreads();
        float zv[4][4] = {};
        for (int d = 0; d < 64; ++d) {
            float4 qa = *(const float4*)(QT + d * 68 + ty * 4);
            float4 kb = *(const float4*)(KV + d * 68 + tx * 4);
            float a[4] = {qa.x, qa.y, qa.z, qa.w};
            float b[4] = {kb.x, kb.y, kb.z, kb.w};
            #pragma unroll
            for (int i = 0; i < 4; i++)
                #pragma unroll
                for (int j = 0; j < 4; j++)
                    zv[i][j] += a[i] * b[j];
        }
        #pragma unroll
        for (int i = 0; i < 4; i++) {
            float tm = fmaxf(fmaxf(zv[i][0], zv[i][1]), fmaxf(zv[i][2], zv[i][3]));
            for (int off = 1; off < 16; off <<= 1) tm = fmaxf(tm, __shfl_xor(tm, off, 16));
            float mn = fmaxf(m[i], tm);
            float ss = __expf(zv[i][0] - mn) + __expf(zv[i][1] - mn) + __expf(zv[i][2] - mn) + __expf(zv[i][3] - mn);
            for (int off = 1; off < 16; off <<= 1) ss += __shfl_xor(ss, off, 16);
            l[i] = l[i] * __expf(m[i] - mn) + ss;
            m[i] = mn;
        }
        __syncthreads();
    }
    float linv[4];
    #pragma unroll
    for (int i = 0; i < 4; i++) linv[i] = 1.f / l[i];

    float Oa[4][4] = {};
    for (int t = 0; t < 16; ++t) {   // pass 2: exact probs, O=P@V, colsums
        long kbase = ((long)bh * 1024 + t * 64) * 64;
        for (int q = tid; q < 1024; q += 256) {
            int c = q >> 4, d4 = (q & 15) * 4;
            float4 v4 = *(const float4*)(K + kbase + c * 64 + d4);
            KV[(d4 + 0) * 68 + c] = v4.x;
            KV[(d4 + 1) * 68 + c] = v4.y;
            KV[(d4 + 2) * 68 + c] = v4.z;
            KV[(d4 + 3) * 68 + c] = v4.w;
        }
        __syncthreads();
        float zv[4][4] = {};
        for (int d = 0; d < 64; ++d) {
            float4 qa = *(const float4*)(QT + d * 68 + ty * 4);
            float4 kb = *(const float4*)(KV + d * 68 + tx * 4);
            float a[4] = {qa.x, qa.y, qa.z, qa.w};
            float b[4] = {kb.x, kb.y, kb.z, kb.w};
            #pragma unroll
            for (int i = 0; i < 4; i++)
                #pragma unroll
                for (int j = 0; j < 4; j++)
                    zv[i][j] += a[i] * b[j];
        }
        float cs[4] = {0.f, 0.f, 0.f, 0.f};
        #pragma unroll
        for (int i = 0; i < 4; i++)
            #pragma unroll
            for (int j = 0; j < 4; j++) {
                float p = __expf(zv[i][j] - m[i]) * linv[i];
                Ps[(ty * 4 + i) * 68 + tx * 4 + j] = p;
                cs[j] += p;
            }
        if (SCORE) {
            #pragma unroll
            for (int j = 0; j < 4; j++) colpart[ty * 64 + tx * 4 + j] = cs[j];
        }
        __syncthreads();
        if (SCORE && tid < 64) {
            float s = 0.f;
            #pragma unroll
            for (int g = 0; g < 16; g++) s += colpart[g * 64 + tid];
            PSC[((long)(bh * 16 + rt) << 10) + t * 64 + tid] = s;
        }
        for (int q = tid; q < 1024; q += 256) {
            int c = q >> 4, d4 = (q & 15) * 4;
            float4 v4 = *(const float4*)(V + kbase + c * 64 + d4);
            *(float4*)(KV + c * 68 + d4) = v4;
        }
        __syncthreads();
        for (int c = 0; c < 64; ++c) {
            float4 vb = *(const float4*)(KV + c * 68 + tx * 4);
            float b[4] = {vb.x, vb.y, vb.z, vb.w};
            float pv[4];
            #pragma unroll
            for (int i = 0; i < 4; i++) pv[i] = Ps[(ty * 4 + i) * 68 + c];
            #pragma unroll
            for (int i = 0; i < 4; i++)
                #pragma unroll
                for (int j = 0; j < 4; j++)
                    Oa[i][j] += pv[i] * b[j];
        }
        __syncthreads();
    }
    #pragma unroll
    for (int i = 0; i < 4; i++) {
        float4 o4 = make_float4(Oa[i][0], Oa[i][1], Oa[i][2], Oa[i][3]);
        *(float4*)(O + qbase + (ty * 4 + i) * 64 + tx * 4) = o4;
    }
}

__global__ __launch_bounds__(256) void score_reduce_kernel(const float* __restrict__ PSC, float* __restrict__ score) {
    int idx = blockIdx.x * 256 + threadIdx.x;
    int bh = idx >> 10, c = idx & 1023;
    float s = 0.f;
    for (int rt = 0; rt < 16; rt++) s += PSC[((long)(bh * 16 + rt) << 10) + c];
    score[idx] = s;
}

__global__ __launch_bounds__(256) void topk_kernel(const float* __restrict__ score, int* __restrict__ topk) {
    __shared__ float s[1024];
    int z = blockIdx.x; int tid = threadIdx.x;
    for (int i = tid; i < 1024; i += 256) {
        float v = score[z * 1024 + i];
        s[i] = (v == v) ? v : -INFINITY;
    }
    __syncthreads();
    for (int i = tid; i < 1024; i += 256) {
        float si = s[i]; int r = 0;
        for (int j = 0; j < 1024; j++) {
            float sj = s[j];
            r += (sj > si) || (sj == si && j < i);
        }
        if (r < 256) topk[z * 256 + r] = i;
    }
}

__global__ __launch_bounds__(256) void gather_tokf_kernel(const float* __restrict__ coarse,
                                                          const int* __restrict__ topk,
                                                          float* __restrict__ tokf) {
    long idx = (long)blockIdx.x * 256 + threadIdx.x;
    int d = (int)(idx & 63); int t = (int)((idx >> 6) & 3);
    int j = (int)((idx >> 8) & 255); int bh = (int)(idx >> 16);
    int p = topk[bh * 256 + j] & 1023;
    int py = p >> 5, px = p & 31;
    int dy = t >> 1, dx = t & 1;
    int b = bh >> 2, h = bh & 3;
    tokf[idx] = coarse[(((long)b * 256 + h * 64 + d) * 64 + (2 * py + dy)) * 64 + (2 * px + dx)];
}

__global__ __launch_bounds__(256) void scatter_add_kernel(float* __restrict__ coarse,
                                                          const int* __restrict__ topk,
                                                          const float* __restrict__ outf) {
    long idx = (long)blockIdx.x * 256 + threadIdx.x;
    int d = (int)(idx & 63); int t = (int)((idx >> 6) & 3);
    int j = (int)((idx >> 8) & 255); int bh = (int)(idx >> 16);
    int p = topk[bh * 256 + j] & 1023;
    int py = p >> 5, px = p & 31;
    int dy = t >> 1, dx = t & 1;
    int b = bh >> 2, h = bh & 3;
    coarse[(((long)b * 256 + h * 64 + d) * 64 + (2 * py + dy)) * 64 + (2 * px + dx)] += outf[idx];
}

__global__ __launch_bounds__(64) void dw_bn_relu6_kernel(const float* __restrict__ y, const float* __restrict__ w9,
                                                         const float* __restrict__ s1, const float* __restrict__ t1,
                                                         float* __restrict__ out) {
    int gid = blockIdx.x;
    int row = gid & 63; int bc = gid >> 6; int c = bc & 255;
    int x = threadIdx.x;
    const float* base = y + (long)bc * 4096;
    float acc = 0.f;
    #pragma unroll
    for (int ky = 0; ky < 3; ky++) {
        int yy = row + ky - 1;
        if (yy < 0 || yy >= 64) continue;
        #pragma unroll
        for (int kx = 0; kx < 3; kx++) {
            int xx = x + kx - 1;
            if (xx < 0 || xx >= 64) continue;
            acc += base[yy * 64 + xx] * w9[c * 9 + ky * 3 + kx];
        }
    }
    out[(long)gid * 64 + x] = relu6(acc * s1[c] + t1[c]);
}

// ---------------- launch ----------------
extern "C" void kernel_launch(void* const* d_in, const int* in_sizes, int n_in,
                              void* d_out, int out_size, void* d_ws, size_t ws_size,
                              hipStream_t stream) {
    if (ws_size < (size_t)WS_FLOATS * 4) return;

    const void* x      = d_in[0];
    const void* down_w = d_in[1];
    const void* down_b = d_in[2];
    const void* up_w   = d_in[3];
    const void* up_b   = d_in[4];
    const void* wqkv_c = d_in[5];
    const void* bqkv_c = d_in[6];
    const void* wqkv_f = d_in[7];
    const void* bqkv_f = d_in[8];
    const void* dw_w   = d_in[9];
    const void* bn1_g  = d_in[10];
    const void* bn1_b  = d_in[11];
    const void* bn1_m  = d_in[12];
    const void* bn1_v  = d_in[13];
    const void* pw_w   = d_in[14];
    const void* bn2_g  = d_in[15];
    const void* bn2_b  = d_in[16];
    const void* bn2_m  = d_in[17];
    const void* bn2_v  = d_in[18];

    float* ws = (float*)d_ws;
    int* flagp = (int*)(ws + OFF_FLAG);
    dim3 blk(256);

    hipMemsetAsync(flagp, 0, sizeof(int), stream);
    detect_kernel<<<1, blk, 0, stream>>>(x, flagp);

    cvt_kernel<<<32768, blk, 0, stream>>>(x, ws + OFF_XF, 8388608, flagp);
    cvt_kernel<<<4096, blk, 0, stream>>>(down_w, ws + OFF_DOWNW, 1048576, flagp);
    cvt_kernel<<<1, blk, 0, stream>>>(down_b, ws + OFF_DOWNB, 256, flagp);
    cvt_kernel<<<1, blk, 0, stream>>>(up_b, ws + OFF_UPB, 256, flagp);
    cvt_kernel<<<1, blk, 0, stream>>>(bqkv_c, ws + OFF_BQKVC, 192, flagp);
    cvt_kernel<<<1, blk, 0, stream>>>(bqkv_f, ws + OFF_BQKVF, 192, flagp);
    cvt_kernel<<<256, blk, 0, stream>>>(pw_w, ws + OFF_PWW, 65536, flagp);
    cvt_kernel<<<9, blk, 0, stream>>>(dw_w, ws + OFF_DWW, 2304, flagp);
    tqkv_kernel<<<48, blk, 0, stream>>>(wqkv_c, ws + OFF_WQKVC, flagp);
    tqkv_kernel<<<48, blk, 0, stream>>>(wqkv_f, ws + OFF_WQKVF, flagp);
    prep_up_kernel<<<4096, blk, 0, stream>>>(up_w, ws + OFF_UPW4, flagp);
    bn_prep_kernel<<<1, blk, 0, stream>>>(bn1_g, bn1_b, bn1_m, bn1_v, ws + OFF_BN1S, ws + OFF_BN1T, flagp);
    bn_prep_kernel<<<1, blk, 0, stream>>>(bn2_g, bn2_b, bn2_m, bn2_v, ws + OFF_BN2S, ws + OFF_BN2T, flagp);

    // down conv (implicit im2col from fp32 XF): M=8192, N=256, K=4096 -> xd NHWC
    gemm_k<1, 1><<<dim3(4, 128, 1), blk, 0, stream>>>(ws + OFF_XF, ws + OFF_DOWNW, ws + OFF_XDHWC,
        4096, 0, 0, 0, 0, 4096, ws + OFF_DOWNB, nullptr, nullptr, nullptr, nullptr, flagp);

    // coarse qkv: M=32768, N=192, K=64 -> Q, K, V [bh][tok][d]
    gemm_k<2, 0><<<dim3(3, 512, 1), blk, 0, stream>>>(ws + OFF_XDHWC, ws + OFF_WQKVC, ws + OFF_Q,
        64, 0, 0, 64, 1, 64, ws + OFF_BQKVC, nullptr, ws + OFF_KK, ws + OFF_V, nullptr, flagp);

    // coarse fused attention (+ colsums) -> OUTC, PSC
    attn_kernel<true><<<dim3(16, 32), blk, 0, stream>>>(ws + OFF_Q, ws + OFF_KK, ws + OFF_V,
        ws + OFF_OUTC, ws + OFF_PSC);
    score_reduce_kernel<<<128, blk, 0, stream>>>(ws + OFF_PSC, ws + OFF_SCORE);
    topk_kernel<<<32, blk, 0, stream>>>(ws + OFF_SCORE, (int*)(ws + OFF_TOPK));

    // up conv (transposed, implicit im2col, z=cls): M=8192, N=256, K=1024 -> coarse NCHW
    gemm_k<4, 2><<<dim3(4, 128, 4), blk, 0, stream>>>(ws + OFF_OUTC, ws + OFF_UPW4, ws + OFF_COARSE,
        1024, 0, 262144, 0, 0, 1024, ws + OFF_UPB, nullptr, nullptr, nullptr, nullptr, flagp);

    // fine attention
    gather_tokf_kernel<<<8192, blk, 0, stream>>>(ws + OFF_COARSE, (const int*)(ws + OFF_TOPK), ws + OFF_XDHWC);
    gemm_k<3, 0><<<dim3(3, 512, 1), blk, 0, stream>>>(ws + OFF_XDHWC, ws + OFF_WQKVF, ws + OFF_Q,
        64, 0, 0, 64, 1, 64, ws + OFF_BQKVF, nullptr, ws + OFF_KK, ws + OFF_V, nullptr, flagp);
    attn_kernel<false><<<dim3(16, 32), blk, 0, stream>>>(ws + OFF_Q, ws + OFF_KK, ws + OFF_V,
        ws + OFF_OUTC, nullptr);
    scatter_add_kernel<<<8192, blk, 0, stream>>>(ws + OFF_COARSE, (const int*)(ws + OFF_TOPK), ws + OFF_OUTC);

    // depthwise + bn1 + relu6 -> T1
    dw_bn_relu6_kernel<<<131072, dim3(64), 0, stream>>>(ws + OFF_COARSE, ws + OFF_DWW,
        ws + OFF_BN1S, ws + OFF_BN1T, ws + OFF_T1);

    // pointwise + bn2 + relu6 -> d_out (dtype per flag): z=8, M=4096, N=256, K=256
    gemm_k<5, 0><<<dim3(4, 64, 8), blk, 0, stream>>>(ws + OFF_T1, ws + OFF_PWW, nullptr,
        256, 1048576, 0, 1, 4096, 256, ws + OFF_BN2S, ws + OFF_BN2T, nullptr, nullptr, d_out, flagp);
}

// Round 9
// 1228.824 us; speedup vs baseline: 1.6028x; 1.1664x over previous
//
#include <hip/hip_runtime.h>
#include <hip/hip_bf16.h>

typedef __hip_bfloat16 bf16;
typedef __bf16 bf16x8 __attribute__((ext_vector_type(8)));
typedef float f32x4 __attribute__((ext_vector_type(4)));

// B=8, C=256, H=W=64, nh=4, HD=64, coarse tokens N=1024 (32x32), kf=256, fine tokens 1024.
// fp32 in/out (auto-detected). Coarse path (pre-topk) fp32-exact; post-topk GEMMs bf16 MFMA.

// ---------------- workspace layout (float offsets), peak 86.5 MB ----------------
#define OFF_XDHWC    0L
#define OFF_Q        2097152L
#define OFF_KK       4194304L
#define OFF_V        6291456L
#define OFF_T1       0L           // overlay on trunk (XDHWC/Q/K/V dead)
#define OFF_OUTC     8388608L
#define OFF_COARSE   10485760L    // xf (fp32 x) first, then coarse NCHW -> y
#define OFF_XF       10485760L
#define OFF_PSC      18874368L
#define OFF_SCORE    19398656L
#define OFF_TOPK     19431424L
#define OFF_DOWNW    19439616L
#define OFF_UPW4     20488192L    // now bf16 (ushort), 1,048,576 entries [cls][co][k]
#define OFF_WQKVC    21536768L
#define OFF_BQKVC    21549056L
#define OFF_WQKVF    21549248L
#define OFF_BQKVF    21561536L
#define OFF_PWW      21561728L    // now bf16 (ushort), 65,536 entries [co][ci]
#define OFF_DWW      21627264L
#define OFF_BN1S     21629568L
#define OFF_BN1T     21629824L
#define OFF_BN2S     21630080L
#define OFF_BN2T     21630336L
#define OFF_DOWNB    21630592L
#define OFF_UPB      21630848L
#define OFF_FLAG     21631104L    // 1 int: 1 = bf16 world, 0 = fp32 world (default via memset)
#define WS_FLOATS    21631360L

__device__ __forceinline__ float relu6(float v) { return v < 0.f ? 0.f : (v > 6.f ? 6.f : v); }

__device__ __forceinline__ float ldin(const void* p, long i, int flag) {
    return flag ? __bfloat162float(((const bf16*)p)[i]) : ((const float*)p)[i];
}

// fp32 -> bf16 bits, round-to-nearest-even
__device__ __forceinline__ unsigned short f2bf(float f) {
    unsigned int b = __float_as_uint(f);
    b += 0x7FFFu + ((b >> 16) & 1u);
    return (unsigned short)(b >> 16);
}

// ---------------- dtype detector ----------------
__global__ __launch_bounds__(256) void detect_kernel(const void* __restrict__ x, int* __restrict__ flag) {
    __shared__ int cnt[256];
    int tid = threadIdx.x;
    int c = 0;
    for (int i = tid; i < 4096; i += 256) {
        long idx = (long)i * 2047;
        float v = __bfloat162float(((const bf16*)x)[idx]);
        float a = fabsf(v);
        if (isfinite(v) && a > 1e-8f && a < 100.f) c++;
    }
    cnt[tid] = c; __syncthreads();
    for (int s = 128; s > 0; s >>= 1) { if (tid < s) cnt[tid] += cnt[tid + s]; __syncthreads(); }
    if (tid == 0 && cnt[0] >= 3686) *flag = 1;
}

// ---------------- prep kernels (dual-dtype) ----------------
__global__ __launch_bounds__(256) void cvt_kernel(const void* __restrict__ in, float* __restrict__ out,
                                                  int n, const int* __restrict__ flagp) {
    int flag = *flagp;
    int i = blockIdx.x * 256 + threadIdx.x;
    if (i < n) out[i] = ldin(in, i, flag);
}

// convert input weights to bf16 bits (for MFMA B operands)
__global__ __launch_bounds__(256) void cvt_bf16_kernel(const void* __restrict__ in, unsigned short* __restrict__ out,
                                                       int n, const int* __restrict__ flagp) {
    int flag = *flagp;
    int i = blockIdx.x * 256 + threadIdx.x;
    if (i < n) out[i] = f2bf(ldin(in, i, flag));
}

__global__ __launch_bounds__(256) void tqkv_kernel(const void* __restrict__ w, float* __restrict__ wt,
                                                   const int* __restrict__ flagp) {
    int flag = *flagp;
    int idx = blockIdx.x * 256 + threadIdx.x;
    if (idx >= 192 * 64) return;
    int j = idx >> 6, d = idx & 63;
    wt[idx] = ldin(w, d * 192 + j, flag);
}

// up_w [ci,co,4,4] -> W4 bf16 [cls][co][ci*4+j]
// parity a=0: jy=0->(ky=1,dy=0), jy=1->(ky=3,dy=-1); a=1: jy=0->(ky=2,dy=0), jy=1->(ky=0,dy=+1)
__global__ __launch_bounds__(256) void prep_up_kernel(const void* __restrict__ w, unsigned short* __restrict__ W4,
                                                      const int* __restrict__ flagp) {
    int flag = *flagp;
    int idx = blockIdx.x * 256 + threadIdx.x;
    int cls = idx >> 18; int rem = idx & 262143;
    int co = rem >> 10; int q = rem & 1023;
    int ci = q >> 2; int j = q & 3;
    int pa = cls >> 1, pb = cls & 1;
    int jy = j >> 1, jx = j & 1;
    int ky = (pa == 0) ? (jy ? 3 : 1) : (jy ? 0 : 2);
    int kx = (pb == 0) ? (jx ? 3 : 1) : (jx ? 0 : 2);
    W4[idx] = f2bf(ldin(w, (((long)ci * 256 + co) * 4 + ky) * 4 + kx, flag));
}

__global__ void bn_prep_kernel(const void* __restrict__ g, const void* __restrict__ b,
                               const void* __restrict__ m, const void* __restrict__ v,
                               float* __restrict__ s, float* __restrict__ t,
                               const int* __restrict__ flagp) {
    int flag = *flagp;
    int c = threadIdx.x;
    float gv = ldin(g, c, flag), bv = ldin(b, c, flag);
    float mv = ldin(m, c, flag), vv = ldin(v, c, flag);
    float inv = gv / sqrtf(vv + 1e-5f);
    s[c] = inv; t[c] = bv - mv * inv;
}

// ---------------- fp32 GEMM (coarse path only): C[m,n] = sum_k A[m,k]*B[n,k] ----------------
template<int EPI, int AMODE>
__global__ __launch_bounds__(256) void gemm_k(
    const float* __restrict__ A, const float* __restrict__ B, float* __restrict__ C,
    int K, long sAz, long sBz, int sAm, int sAk, int sBn,
    const float* __restrict__ e0, const float* __restrict__ e1,
    float* __restrict__ o1, float* __restrict__ o2, void* __restrict__ ob,
    const int* __restrict__ flagp)
{
    __shared__ float As[16][68];
    __shared__ float Bs[16][68];
    int z = blockIdx.z;
    if (AMODE == 0) A += (long)z * sAz;
    B += (long)z * sBz;
    int m0 = blockIdx.y * 64;
    int n0 = blockIdx.x * 64;
    int tid = threadIdx.x;
    int tx = tid & 15, ty = tid >> 4;
    int l4 = tid >> 2, kq = (tid & 3) * 4;
    float aR[4];
    float4 bR;

    auto loadA = [&](int k0) {
        if (AMODE == 0) {
            if (sAk == 1) {
                float4 v4 = *(const float4*)(A + (long)(m0 + l4) * sAm + (k0 + kq));
                aR[0] = v4.x; aR[1] = v4.y; aR[2] = v4.z; aR[3] = v4.w;
            } else {
                #pragma unroll
                for (int i = 0; i < 4; i++) {
                    int idx = i * 256 + tid;
                    int ml = idx & 63, kl = idx >> 6;
                    aR[i] = A[(long)(m0 + ml) * sAm + (long)(k0 + kl) * sAk];
                }
            }
        } else {  // AMODE 1: xf[b,c,iy,ix], m=(b,oy,ox), k=(c,ky,kx)
            #pragma unroll
            for (int i = 0; i < 4; i++) {
                int idx = i * 256 + tid;
                int kl = idx & 15, ml = idx >> 4;
                int m = m0 + ml, k = k0 + kl;
                int b = m >> 10, oy = (m >> 5) & 31, ox = m & 31;
                int c = k >> 4, ky = (k >> 2) & 3, kx = k & 3;
                int iy = 2 * oy - 1 + ky, ix = 2 * ox - 1 + kx;
                float val = 0.f;
                if ((unsigned)iy < 64u && (unsigned)ix < 64u)
                    val = A[(((long)b * 256 + c) * 64 + iy) * 64 + ix];
                aR[i] = val;
            }
        }
    };
    auto storeA = [&]() {
        if (AMODE == 0 && sAk == 1) {
            As[kq + 0][l4] = aR[0];
            As[kq + 1][l4] = aR[1];
            As[kq + 2][l4] = aR[2];
            As[kq + 3][l4] = aR[3];
        } else if (AMODE == 0) {
            #pragma unroll
            for (int i = 0; i < 4; i++) {
                int idx = i * 256 + tid;
                int ml = idx & 63, kl = idx >> 6;
                As[kl][ml] = aR[i];
            }
        } else {
            #pragma unroll
            for (int i = 0; i < 4; i++) {
                int idx = i * 256 + tid;
                int kl = idx & 15, ml = idx >> 4;
                As[kl][ml] = aR[i];
            }
        }
    };
    auto loadB = [&](int k0) {
        bR = *(const float4*)(B + (long)(n0 + l4) * sBn + (k0 + kq));
    };

    float acc[4][4] = {};
    loadA(0); loadB(0);
    for (int k0 = 0; k0 < K; k0 += 16) {
        storeA();
        Bs[kq + 0][l4] = bR.x;
        Bs[kq + 1][l4] = bR.y;
        Bs[kq + 2][l4] = bR.z;
        Bs[kq + 3][l4] = bR.w;
        __syncthreads();
        if (k0 + 16 < K) { loadA(k0 + 16); loadB(k0 + 16); }
        #pragma unroll
        for (int kk = 0; kk < 16; ++kk) {
            float4 av = *reinterpret_cast<const float4*>(&As[kk][ty * 4]);
            float4 bv = *reinterpret_cast<const float4*>(&Bs[kk][tx * 4]);
            float a[4] = {av.x, av.y, av.z, av.w};
            float b[4] = {bv.x, bv.y, bv.z, bv.w};
            #pragma unroll
            for (int i = 0; i < 4; i++)
                #pragma unroll
                for (int j = 0; j < 4; j++)
                    acc[i][j] += a[i] * b[j];
        }
        __syncthreads();
    }
    #pragma unroll
    for (int i = 0; i < 4; i++) {
        int m = m0 + ty * 4 + i;
        #pragma unroll
        for (int j = 0; j < 4; j++) {
            int n = n0 + tx * 4 + j;
            float v = acc[i][j];
            if (EPI == 1) {
                C[(long)m * 256 + n] = v + e0[n];
            } else if (EPI == 2 || EPI == 3) {
                v += e0[n];
                int bh, tok;
                if (EPI == 2) { int bi = m >> 12; int h = m & 3; tok = (m >> 2) & 1023; bh = bi * 4 + h; }
                else          { bh = m >> 10; tok = m & 1023; }
                long base = ((long)bh * 1024 + tok) * 64;
                if (n < 64) C[base + n] = v;
                else if (n < 128) o1[base + (n - 64)] = v;
                else o2[base + (n - 128)] = v;
            }
        }
    }
}

// ---------------- bf16 MFMA GEMM (post-topk): C[m,n] = sum_k A[m,k]*B[n,k] ----------------
// 64x64 tile, 4 waves, each wave = 16-row strip; 16x16x32 MFMA, fp32 accumulate.
// AMODE 0: A m-contig/k-strided fp32 (pw). AMODE 2: implicit im2col gather from OUTC (up conv, z=cls).
// EPI 4: +bias, conv-T scatter to NCHW. EPI 5: bn+relu6 -> d_out (dtype per flag).
template<int EPI, int AMODE>
__global__ __launch_bounds__(256) void gemm_mfma(
    const float* __restrict__ A, const unsigned short* __restrict__ Bb, float* __restrict__ C,
    int K, long sAz, long sBz, int sAk, int sBn,
    const float* __restrict__ e0, const float* __restrict__ e1,
    void* __restrict__ ob, const int* __restrict__ flagp)
{
    __shared__ __align__(16) unsigned short Asb[64 * 40];
    __shared__ __align__(16) unsigned short Bsb[64 * 40];
    int z = blockIdx.z;
    if (AMODE == 0) A += (long)z * sAz;
    Bb += (long)z * sBz;
    int m0 = blockIdx.y * 64, n0 = blockIdx.x * 64;
    int tid = threadIdx.x;
    int w = tid >> 6, l = tid & 63;
    int l15 = l & 15, q = l >> 4;
    float aR[8];
    uint4 bR;

    auto loadA = [&](int k0) {
        if (AMODE == 0) {
            #pragma unroll
            for (int i = 0; i < 8; i++) {
                int idx = i * 256 + tid;
                int ml = idx & 63, kl = idx >> 6;
                aR[i] = A[(long)(k0 + kl) * sAk + (m0 + ml)];
            }
        } else {  // gather from OUTC [bh][tok][d]; m=(b,y,x), k=(ci,j), cls=z
            #pragma unroll
            for (int i = 0; i < 8; i++) {
                int idx = i * 256 + tid;
                int kl = idx & 31, ml = idx >> 5;
                int m = m0 + ml, k = k0 + kl;
                int b = m >> 10, y = (m >> 5) & 31, x2 = m & 31;
                int ci = k >> 2, j = k & 3;
                int pa = z >> 1, pb = z & 1;
                int jy = j >> 1, jx = j & 1;
                int dy = (pa == 0) ? (jy ? -1 : 0) : (jy ? 1 : 0);
                int dx = (pb == 0) ? (jx ? -1 : 0) : (jx ? 1 : 0);
                int yy = y + dy, xx = x2 + dx;
                float val = 0.f;
                if ((unsigned)yy < 32u && (unsigned)xx < 32u)
                    val = A[(((long)b * 4 + (ci >> 6)) * 1024 + yy * 32 + xx) * 64 + (ci & 63)];
                aR[i] = val;
            }
        }
    };
    auto storeA = [&]() {
        #pragma unroll
        for (int i = 0; i < 8; i++) {
            int idx = i * 256 + tid;
            int ml, kl;
            if (AMODE == 0) { ml = idx & 63; kl = idx >> 6; }
            else            { kl = idx & 31; ml = idx >> 5; }
            Asb[ml * 40 + kl] = f2bf(aR[i]);
        }
    };
    int bn = tid >> 2, bk = (tid & 3) * 8;
    auto loadB = [&](int k0) {
        bR = *(const uint4*)(Bb + (long)(n0 + bn) * sBn + (k0 + bk));
    };

    f32x4 acc[4] = {};
    loadA(0); loadB(0);
    for (int k0 = 0; k0 < K; k0 += 32) {
        storeA();
        *(uint4*)(&Bsb[bn * 40 + bk]) = bR;
        __syncthreads();
        if (k0 + 32 < K) { loadA(k0 + 32); loadB(k0 + 32); }
        bf16x8 af = *(const bf16x8*)(&Asb[(w * 16 + l15) * 40 + q * 8]);
        #pragma unroll
        for (int j4 = 0; j4 < 4; j4++) {
            bf16x8 bf = *(const bf16x8*)(&Bsb[(j4 * 16 + l15) * 40 + q * 8]);
            acc[j4] = __builtin_amdgcn_mfma_f32_16x16x32_bf16(af, bf, acc[j4], 0, 0, 0);
        }
        __syncthreads();
    }
    int oflag = (EPI == 5) ? *flagp : 0;
    #pragma unroll
    for (int j4 = 0; j4 < 4; j4++) {
        int n = n0 + j4 * 16 + l15;
        #pragma unroll
        for (int r = 0; r < 4; r++) {
            int m = m0 + w * 16 + q * 4 + r;
            float v = acc[j4][r];
            if (EPI == 4) {
                v += e0[n];
                int pa = z >> 1, pb = z & 1;
                int bi = m >> 10, y = (m >> 5) & 31, x2 = m & 31;
                C[(((long)bi * 256 + n) * 64 + (2 * y + pa)) * 64 + (2 * x2 + pb)] = v;
            } else {
                v = relu6(v * e0[n] + e1[n]);
                long oidx = (long)z * 1048576 + (long)n * 4096 + m;
                if (oflag) ((bf16*)ob)[oidx] = __float2bfloat16(v);
                else       ((float*)ob)[oidx] = v;
            }
        }
    }
}

// ---------------- fused two-pass attention: [bh=32][N=1024][D=64], scale 1/8 folded into Q ----------------
template<bool SCORE>
__global__ __launch_bounds__(256) void attn_kernel(
    const float* __restrict__ Q, const float* __restrict__ K, const float* __restrict__ V,
    float* __restrict__ O, float* __restrict__ PSC)
{
    __shared__ __align__(16) float QT[64 * 68];
    __shared__ __align__(16) float KV[64 * 68];
    __shared__ __align__(16) float Ps[64 * 68];
    __shared__ float colpart[16 * 64];
    int bh = blockIdx.y, rt = blockIdx.x;
    int tid = threadIdx.x;
    int tx = tid & 15, ty = tid >> 4;
    long qbase = ((long)bh * 1024 + rt * 64) * 64;
    for (int q = tid; q < 1024; q += 256) {
        int r = q >> 4, d4 = (q & 15) * 4;
        float4 v4 = *(const float4*)(Q + qbase + r * 64 + d4);
        QT[(d4 + 0) * 68 + r] = v4.x * 0.125f;
        QT[(d4 + 1) * 68 + r] = v4.y * 0.125f;
        QT[(d4 + 2) * 68 + r] = v4.z * 0.125f;
        QT[(d4 + 3) * 68 + r] = v4.w * 0.125f;
    }
    float m[4], l[4];
    #pragma unroll
    for (int i = 0; i < 4; i++) { m[i] = -1e30f; l[i] = 0.f; }
    __syncthreads();

    for (int t = 0; t < 16; ++t) {
        long kbase = ((long)bh * 1024 + t * 64) * 64;
        for (int q = tid; q < 1024; q += 256) {
            int c = q >> 4, d4 = (q & 15) * 4;
            float4 v4 = *(const float4*)(K + kbase + c * 64 + d4);
            KV[(d4 + 0) * 68 + c] = v4.x;
            KV[(d4 + 1) * 68 + c] = v4.y;
            KV[(d4 + 2) * 68 + c] = v4.z;
            KV[(d4 + 3) * 68 + c] = v4.w;
        }
        __syncthreads();
        float zv[4][4] = {};
        for (int d = 0; d < 64; ++d) {
            float4 qa = *(const float4*)(QT + d * 68 + ty * 4);
            float4 kb = *(const float4*)(KV + d * 68 + tx * 4);
            float a[4] = {qa.x, qa.y, qa.z, qa.w};
            float b[4] = {kb.x, kb.y, kb.z, kb.w};
            #pragma unroll
            for (int i = 0; i < 4; i++)
                #pragma unroll
                for (int j = 0; j < 4; j++)
                    zv[i][j] += a[i] * b[j];
        }
        #pragma unroll
        for (int i = 0; i < 4; i++) {
            float tm = fmaxf(fmaxf(zv[i][0], zv[i][1]), fmaxf(zv[i][2], zv[i][3]));
            for (int off = 1; off < 16; off <<= 1) tm = fmaxf(tm, __shfl_xor(tm, off, 16));
            float mn = fmaxf(m[i], tm);
            float ss = __expf(zv[i][0] - mn) + __expf(zv[i][1] - mn) + __expf(zv[i][2] - mn) + __expf(zv[i][3] - mn);
            for (int off = 1; off < 16; off <<= 1) ss += __shfl_xor(ss, off, 16);
            l[i] = l[i] * __expf(m[i] - mn) + ss;
            m[i] = mn;
        }
        __syncthreads();
    }
    float linv[4];
    #pragma unroll
    for (int i = 0; i < 4; i++) linv[i] = 1.f / l[i];

    float Oa[4][4] = {};
    for (int t = 0; t < 16; ++t) {
        long kbase = ((long)bh * 1024 + t * 64) * 64;
        for (int q = tid; q < 1024; q += 256) {
            int c = q >> 4, d4 = (q & 15) * 4;
            float4 v4 = *(const float4*)(K + kbase + c * 64 + d4);
            KV[(d4 + 0) * 68 + c] = v4.x;
            KV[(d4 + 1) * 68 + c] = v4.y;
            KV[(d4 + 2) * 68 + c] = v4.z;
            KV[(d4 + 3) * 68 + c] = v4.w;
        }
        __syncthreads();
        float zv[4][4] = {};
        for (int d = 0; d < 64; ++d) {
            float4 qa = *(const float4*)(QT + d * 68 + ty * 4);
            float4 kb = *(const float4*)(KV + d * 68 + tx * 4);
            float a[4] = {qa.x, qa.y, qa.z, qa.w};
            float b[4] = {kb.x, kb.y, kb.z, kb.w};
            #pragma unroll
            for (int i = 0; i < 4; i++)
                #pragma unroll
                for (int j = 0; j < 4; j++)
                    zv[i][j] += a[i] * b[j];
        }
        float cs[4] = {0.f, 0.f, 0.f, 0.f};
        #pragma unroll
        for (int i = 0; i < 4; i++)
            #pragma unroll
            for (int j = 0; j < 4; j++) {
                float p = __expf(zv[i][j] - m[i]) * linv[i];
                Ps[(ty * 4 + i) * 68 + tx * 4 + j] = p;
                cs[j] += p;
            }
        if (SCORE) {
            #pragma unroll
            for (int j = 0; j < 4; j++) colpart[ty * 64 + tx * 4 + j] = cs[j];
        }
        __syncthreads();
        if (SCORE && tid < 64) {
            float s = 0.f;
            #pragma unroll
            for (int g = 0; g < 16; g++) s += colpart[g * 64 + tid];
            PSC[((long)(bh * 16 + rt) << 10) + t * 64 + tid] = s;
        }
        for (int q = tid; q < 1024; q += 256) {
            int c = q >> 4, d4 = (q & 15) * 4;
            float4 v4 = *(const float4*)(V + kbase + c * 64 + d4);
            *(float4*)(KV + c * 68 + d4) = v4;
        }
        __syncthreads();
        for (int c = 0; c < 64; ++c) {
            float4 vb = *(const float4*)(KV + c * 68 + tx * 4);
            float b[4] = {vb.x, vb.y, vb.z, vb.w};
            float pv[4];
            #pragma unroll
            for (int i = 0; i < 4; i++) pv[i] = Ps[(ty * 4 + i) * 68 + c];
            #pragma unroll
            for (int i = 0; i < 4; i++)
                #pragma unroll
                for (int j = 0; j < 4; j++)
                    Oa[i][j] += pv[i] * b[j];
        }
        __syncthreads();
    }
    #pragma unroll
    for (int i = 0; i < 4; i++) {
        float4 o4 = make_float4(Oa[i][0], Oa[i][1], Oa[i][2], Oa[i][3]);
        *(float4*)(O + qbase + (ty * 4 + i) * 64 + tx * 4) = o4;
    }
}

__global__ __launch_bounds__(256) void score_reduce_kernel(const float* __restrict__ PSC, float* __restrict__ score) {
    int idx = blockIdx.x * 256 + threadIdx.x;
    int bh = idx >> 10, c = idx & 1023;
    float s = 0.f;
    for (int rt = 0; rt < 16; rt++) s += PSC[((long)(bh * 16 + rt) << 10) + c];
    score[idx] = s;
}

__global__ __launch_bounds__(256) void topk_kernel(const float* __restrict__ score, int* __restrict__ topk) {
    __shared__ float s[1024];
    int z = blockIdx.x; int tid = threadIdx.x;
    for (int i = tid; i < 1024; i += 256) {
        float v = score[z * 1024 + i];
        s[i] = (v == v) ? v : -INFINITY;
    }
    __syncthreads();
    for (int i = tid; i < 1024; i += 256) {
        float si = s[i]; int r = 0;
        for (int j = 0; j < 1024; j++) {
            float sj = s[j];
            r += (sj > si) || (sj == si && j < i);
        }
        if (r < 256) topk[z * 256 + r] = i;
    }
}

__global__ __launch_bounds__(256) void gather_tokf_kernel(const float* __restrict__ coarse,
                                                          const int* __restrict__ topk,
                                                          float* __restrict__ tokf) {
    long idx = (long)blockIdx.x * 256 + threadIdx.x;
    int d = (int)(idx & 63); int t = (int)((idx >> 6) & 3);
    int j = (int)((idx >> 8) & 255); int bh = (int)(idx >> 16);
    int p = topk[bh * 256 + j] & 1023;
    int py = p >> 5, px = p & 31;
    int dy = t >> 1, dx = t & 1;
    int b = bh >> 2, h = bh & 3;
    tokf[idx] = coarse[(((long)b * 256 + h * 64 + d) * 64 + (2 * py + dy)) * 64 + (2 * px + dx)];
}

__global__ __launch_bounds__(256) void scatter_add_kernel(float* __restrict__ coarse,
                                                          const int* __restrict__ topk,
                                                          const float* __restrict__ outf) {
    long idx = (long)blockIdx.x * 256 + threadIdx.x;
    int d = (int)(idx & 63); int t = (int)((idx >> 6) & 3);
    int j = (int)((idx >> 8) & 255); int bh = (int)(idx >> 16);
    int p = topk[bh * 256 + j] & 1023;
    int py = p >> 5, px = p & 31;
    int dy = t >> 1, dx = t & 1;
    int b = bh >> 2, h = bh & 3;
    coarse[(((long)b * 256 + h * 64 + d) * 64 + (2 * py + dy)) * 64 + (2 * px + dx)] += outf[idx];
}

__global__ __launch_bounds__(64) void dw_bn_relu6_kernel(const float* __restrict__ y, const float* __restrict__ w9,
                                                         const float* __restrict__ s1, const float* __restrict__ t1,
                                                         float* __restrict__ out) {
    int gid = blockIdx.x;
    int row = gid & 63; int bc = gid >> 6; int c = bc & 255;
    int x = threadIdx.x;
    const float* base = y + (long)bc * 4096;
    float acc = 0.f;
    #pragma unroll
    for (int ky = 0; ky < 3; ky++) {
        int yy = row + ky - 1;
        if (yy < 0 || yy >= 64) continue;
        #pragma unroll
        for (int kx = 0; kx < 3; kx++) {
            int xx = x + kx - 1;
            if (xx < 0 || xx >= 64) continue;
            acc += base[yy * 64 + xx] * w9[c * 9 + ky * 3 + kx];
        }
    }
    out[(long)gid * 64 + x] = relu6(acc * s1[c] + t1[c]);
}

// ---------------- launch ----------------
extern "C" void kernel_launch(void* const* d_in, const int* in_sizes, int n_in,
                              void* d_out, int out_size, void* d_ws, size_t ws_size,
                              hipStream_t stream) {
    if (ws_size < (size_t)WS_FLOATS * 4) return;

    const void* x      = d_in[0];
    const void* down_w = d_in[1];
    const void* down_b = d_in[2];
    const void* up_w   = d_in[3];
    const void* up_b   = d_in[4];
    const void* wqkv_c = d_in[5];
    const void* bqkv_c = d_in[6];
    const void* wqkv_f = d_in[7];
    const void* bqkv_f = d_in[8];
    const void* dw_w   = d_in[9];
    const void* bn1_g  = d_in[10];
    const void* bn1_b  = d_in[11];
    const void* bn1_m  = d_in[12];
    const void* bn1_v  = d_in[13];
    const void* pw_w   = d_in[14];
    const void* bn2_g  = d_in[15];
    const void* bn2_b  = d_in[16];
    const void* bn2_m  = d_in[17];
    const void* bn2_v  = d_in[18];

    float* ws = (float*)d_ws;
    int* flagp = (int*)(ws + OFF_FLAG);
    dim3 blk(256);

    hipMemsetAsync(flagp, 0, sizeof(int), stream);
    detect_kernel<<<1, blk, 0, stream>>>(x, flagp);

    cvt_kernel<<<32768, blk, 0, stream>>>(x, ws + OFF_XF, 8388608, flagp);
    cvt_kernel<<<4096, blk, 0, stream>>>(down_w, ws + OFF_DOWNW, 1048576, flagp);
    cvt_kernel<<<1, blk, 0, stream>>>(down_b, ws + OFF_DOWNB, 256, flagp);
    cvt_kernel<<<1, blk, 0, stream>>>(up_b, ws + OFF_UPB, 256, flagp);
    cvt_kernel<<<1, blk, 0, stream>>>(bqkv_c, ws + OFF_BQKVC, 192, flagp);
    cvt_kernel<<<1, blk, 0, stream>>>(bqkv_f, ws + OFF_BQKVF, 192, flagp);
    cvt_bf16_kernel<<<256, blk, 0, stream>>>(pw_w, (unsigned short*)(ws + OFF_PWW), 65536, flagp);
    cvt_kernel<<<9, blk, 0, stream>>>(dw_w, ws + OFF_DWW, 2304, flagp);
    tqkv_kernel<<<48, blk, 0, stream>>>(wqkv_c, ws + OFF_WQKVC, flagp);
    tqkv_kernel<<<48, blk, 0, stream>>>(wqkv_f, ws + OFF_WQKVF, flagp);
    prep_up_kernel<<<4096, blk, 0, stream>>>(up_w, (unsigned short*)(ws + OFF_UPW4), flagp);
    bn_prep_kernel<<<1, blk, 0, stream>>>(bn1_g, bn1_b, bn1_m, bn1_v, ws + OFF_BN1S, ws + OFF_BN1T, flagp);
    bn_prep_kernel<<<1, blk, 0, stream>>>(bn2_g, bn2_b, bn2_m, bn2_v, ws + OFF_BN2S, ws + OFF_BN2T, flagp);

    // down conv (fp32, topk-critical): M=8192, N=256, K=4096 -> xd NHWC
    gemm_k<1, 1><<<dim3(4, 128, 1), blk, 0, stream>>>(ws + OFF_XF, ws + OFF_DOWNW, ws + OFF_XDHWC,
        4096, 0, 0, 0, 0, 4096, ws + OFF_DOWNB, nullptr, nullptr, nullptr, nullptr, flagp);

    // coarse qkv (fp32): M=32768, N=192, K=64 -> Q, K, V [bh][tok][d]
    gemm_k<2, 0><<<dim3(3, 512, 1), blk, 0, stream>>>(ws + OFF_XDHWC, ws + OFF_WQKVC, ws + OFF_Q,
        64, 0, 0, 64, 1, 64, ws + OFF_BQKVC, nullptr, ws + OFF_KK, ws + OFF_V, nullptr, flagp);

    // coarse fused attention (+ colsums) -> OUTC, PSC
    attn_kernel<true><<<dim3(16, 32), blk, 0, stream>>>(ws + OFF_Q, ws + OFF_KK, ws + OFF_V,
        ws + OFF_OUTC, ws + OFF_PSC);
    score_reduce_kernel<<<128, blk, 0, stream>>>(ws + OFF_PSC, ws + OFF_SCORE);
    topk_kernel<<<32, blk, 0, stream>>>(ws + OFF_SCORE, (int*)(ws + OFF_TOPK));

    // up conv (bf16 MFMA, post-topk): M=8192, N=256, K=1024, z=cls -> coarse NCHW
    gemm_mfma<4, 2><<<dim3(4, 128, 4), blk, 0, stream>>>(ws + OFF_OUTC, (unsigned short*)(ws + OFF_UPW4),
        ws + OFF_COARSE, 1024, 0, 262144, 0, 1024, ws + OFF_UPB, nullptr, nullptr, flagp);

    // fine attention (fp32)
    gather_tokf_kernel<<<8192, blk, 0, stream>>>(ws + OFF_COARSE, (const int*)(ws + OFF_TOPK), ws + OFF_XDHWC);
    gemm_k<3, 0><<<dim3(3, 512, 1), blk, 0, stream>>>(ws + OFF_XDHWC, ws + OFF_WQKVF, ws + OFF_Q,
        64, 0, 0, 64, 1, 64, ws + OFF_BQKVF, nullptr, ws + OFF_KK, ws + OFF_V, nullptr, flagp);
    attn_kernel<false><<<dim3(16, 32), blk, 0, stream>>>(ws + OFF_Q, ws + OFF_KK, ws + OFF_V,
        ws + OFF_OUTC, nullptr);
    scatter_add_kernel<<<8192, blk, 0, stream>>>(ws + OFF_COARSE, (const int*)(ws + OFF_TOPK), ws + OFF_OUTC);

    // depthwise + bn1 + relu6 -> T1
    dw_bn_relu6_kernel<<<131072, dim3(64), 0, stream>>>(ws + OFF_COARSE, ws + OFF_DWW,
        ws + OFF_BN1S, ws + OFF_BN1T, ws + OFF_T1);

    // pointwise + bn2 + relu6 (bf16 MFMA) -> d_out: M=4096, N=256, K=256, z=batch
    gemm_mfma<5, 0><<<dim3(4, 64, 8), blk, 0, stream>>>(ws + OFF_T1, (unsigned short*)(ws + OFF_PWW),
        nullptr, 256, 1048576, 0, 4096, 256, ws + OFF_BN2S, ws + OFF_BN2T, d_out, flagp);
}

// Round 10
// 1078.335 us; speedup vs baseline: 1.8265x; 1.1396x over previous
//
#include <hip/hip_runtime.h>
#include <hip/hip_bf16.h>

typedef __hip_bfloat16 bf16;
typedef __bf16 bf16x8 __attribute__((ext_vector_type(8)));
typedef float f32x4 __attribute__((ext_vector_type(4)));

// B=8, C=256, H=W=64, nh=4, HD=64, coarse tokens N=1024 (32x32), kf=256, fine tokens 1024.
// fp32 in/out (auto-detected). Top-k-critical down-conv uses bf16x2 split-precision MFMA
// (error ~2^-17, fp32-class => tie-safe); post-topk GEMMs plain bf16 MFMA.

// ---------------- workspace layout (float offsets), peak 86.5 MB ----------------
#define OFF_XDHWC    0L
#define OFF_Q        2097152L
#define OFF_KK       4194304L
#define OFF_V        6291456L
#define OFF_T1       0L           // overlay on trunk (XDHWC/Q/K/V dead)
#define OFF_OUTC     8388608L
#define OFF_COARSE   10485760L    // XHL (packed hi|lo x) first, then coarse NCHW -> y
#define OFF_XHL      10485760L    // 8,388,608 uint (hi|lo packed bf16 of x)
#define OFF_PSC      18874368L
#define OFF_SCORE    19398656L
#define OFF_TOPK     19431424L
#define OFF_DOWNW    19439616L    // WH bf16 [co][k] (1M ushort); WL at +524288 floats
#define OFF_DOWNWL   19963904L
#define OFF_UPW4     20488192L    // bf16 (ushort) [cls][co][k]
#define OFF_WQKVC    21536768L
#define OFF_BQKVC    21549056L
#define OFF_WQKVF    21549248L
#define OFF_BQKVF    21561536L
#define OFF_PWW      21561728L    // bf16 (ushort) [co][ci]
#define OFF_DWW      21627264L
#define OFF_BN1S     21629568L
#define OFF_BN1T     21629824L
#define OFF_BN2S     21630080L
#define OFF_BN2T     21630336L
#define OFF_DOWNB    21630592L
#define OFF_UPB      21630848L
#define OFF_FLAG     21631104L    // 1 int: 1 = bf16 world, 0 = fp32 world (default via memset)
#define WS_FLOATS    21631360L

__device__ __forceinline__ float relu6(float v) { return v < 0.f ? 0.f : (v > 6.f ? 6.f : v); }

__device__ __forceinline__ float ldin(const void* p, long i, int flag) {
    return flag ? __bfloat162float(((const bf16*)p)[i]) : ((const float*)p)[i];
}

// fp32 -> bf16 bits, round-to-nearest-even
__device__ __forceinline__ unsigned short f2bf(float f) {
    unsigned int b = __float_as_uint(f);
    b += 0x7FFFu + ((b >> 16) & 1u);
    return (unsigned short)(b >> 16);
}

// ---------------- dtype detector ----------------
__global__ __launch_bounds__(256) void detect_kernel(const void* __restrict__ x, int* __restrict__ flag) {
    __shared__ int cnt[256];
    int tid = threadIdx.x;
    int c = 0;
    for (int i = tid; i < 4096; i += 256) {
        long idx = (long)i * 2047;
        float v = __bfloat162float(((const bf16*)x)[idx]);
        float a = fabsf(v);
        if (isfinite(v) && a > 1e-8f && a < 100.f) c++;
    }
    cnt[tid] = c; __syncthreads();
    for (int s = 128; s > 0; s >>= 1) { if (tid < s) cnt[tid] += cnt[tid + s]; __syncthreads(); }
    if (tid == 0 && cnt[0] >= 3686) *flag = 1;
}

// ---------------- prep kernels (dual-dtype) ----------------
__global__ __launch_bounds__(256) void cvt_kernel(const void* __restrict__ in, float* __restrict__ out,
                                                  int n, const int* __restrict__ flagp) {
    int flag = *flagp;
    int i = blockIdx.x * 256 + threadIdx.x;
    if (i < n) out[i] = ldin(in, i, flag);
}

__global__ __launch_bounds__(256) void cvt_bf16_kernel(const void* __restrict__ in, unsigned short* __restrict__ out,
                                                       int n, const int* __restrict__ flagp) {
    int flag = *flagp;
    int i = blockIdx.x * 256 + threadIdx.x;
    if (i < n) out[i] = f2bf(ldin(in, i, flag));
}

// split to packed hi|lo uint (x): low16 = bf16(v), high16 = bf16(v - hi)
__global__ __launch_bounds__(256) void split_pack_kernel(const void* __restrict__ in, unsigned int* __restrict__ out,
                                                         int n, const int* __restrict__ flagp) {
    int flag = *flagp;
    int i = blockIdx.x * 256 + threadIdx.x;
    if (i < n) {
        float v = ldin(in, i, flag);
        unsigned short h = f2bf(v);
        float fh = __uint_as_float(((unsigned int)h) << 16);
        unsigned short l = f2bf(v - fh);
        out[i] = (unsigned int)h | ((unsigned int)l << 16);
    }
}

// split to separate hi/lo planes (down_w, layout [co][k] is identity with input flat layout)
__global__ __launch_bounds__(256) void split_kernel(const void* __restrict__ in,
                                                    unsigned short* __restrict__ hi, unsigned short* __restrict__ lo,
                                                    int n, const int* __restrict__ flagp) {
    int flag = *flagp;
    int i = blockIdx.x * 256 + threadIdx.x;
    if (i < n) {
        float v = ldin(in, i, flag);
        unsigned short h = f2bf(v);
        float fh = __uint_as_float(((unsigned int)h) << 16);
        hi[i] = h;
        lo[i] = f2bf(v - fh);
    }
}

__global__ __launch_bounds__(256) void tqkv_kernel(const void* __restrict__ w, float* __restrict__ wt,
                                                   const int* __restrict__ flagp) {
    int flag = *flagp;
    int idx = blockIdx.x * 256 + threadIdx.x;
    if (idx >= 192 * 64) return;
    int j = idx >> 6, d = idx & 63;
    wt[idx] = ldin(w, d * 192 + j, flag);
}

// up_w [ci,co,4,4] -> W4 bf16 [cls][co][ci*4+j]
__global__ __launch_bounds__(256) void prep_up_kernel(const void* __restrict__ w, unsigned short* __restrict__ W4,
                                                      const int* __restrict__ flagp) {
    int flag = *flagp;
    int idx = blockIdx.x * 256 + threadIdx.x;
    int cls = idx >> 18; int rem = idx & 262143;
    int co = rem >> 10; int q = rem & 1023;
    int ci = q >> 2; int j = q & 3;
    int pa = cls >> 1, pb = cls & 1;
    int jy = j >> 1, jx = j & 1;
    int ky = (pa == 0) ? (jy ? 3 : 1) : (jy ? 0 : 2);
    int kx = (pb == 0) ? (jx ? 3 : 1) : (jx ? 0 : 2);
    W4[idx] = f2bf(ldin(w, (((long)ci * 256 + co) * 4 + ky) * 4 + kx, flag));
}

__global__ void bn_prep_kernel(const void* __restrict__ g, const void* __restrict__ b,
                               const void* __restrict__ m, const void* __restrict__ v,
                               float* __restrict__ s, float* __restrict__ t,
                               const int* __restrict__ flagp) {
    int flag = *flagp;
    int c = threadIdx.x;
    float gv = ldin(g, c, flag), bv = ldin(b, c, flag);
    float mv = ldin(m, c, flag), vv = ldin(v, c, flag);
    float inv = gv / sqrtf(vv + 1e-5f);
    s[c] = inv; t[c] = bv - mv * inv;
}

// ---------------- bf16x2 split-precision MFMA down-conv (top-k-safe) ----------------
// C[m,n] = conv; m=(b,oy,ox) M=8192, n=co N=256, k=(ci,ky,kx) K=4096. 64x64 tile, BK=32.
// A from XHL (packed hi|lo), B from WH/WL. 3-term MFMA: hihi + hilo + lohi.
__global__ __launch_bounds__(256) void gemm_mfma_x2(
    const unsigned int* __restrict__ XHL,
    const unsigned short* __restrict__ WH, const unsigned short* __restrict__ WL,
    float* __restrict__ C, const float* __restrict__ e0)
{
    __shared__ __align__(16) unsigned short Ah[64 * 40];
    __shared__ __align__(16) unsigned short Al[64 * 40];
    __shared__ __align__(16) unsigned short Bh[64 * 40];
    __shared__ __align__(16) unsigned short Bl[64 * 40];
    int m0 = blockIdx.y * 64, n0 = blockIdx.x * 64;
    int tid = threadIdx.x;
    int w = tid >> 6, l = tid & 63, l15 = l & 15, q = l >> 4;
    unsigned int aR[8];
    uint4 bhR, blR;
    int bn = tid >> 2, bk = (tid & 3) * 8;

    auto loadA = [&](int k0) {
        #pragma unroll
        for (int i = 0; i < 8; i++) {
            int idx = i * 256 + tid;
            int kl = idx & 31, ml = idx >> 5;
            int m = m0 + ml, k = k0 + kl;
            int b = m >> 10, oy = (m >> 5) & 31, ox = m & 31;
            int c = k >> 4, ky = (k >> 2) & 3, kx = k & 3;
            int iy = 2 * oy - 1 + ky, ix = 2 * ox - 1 + kx;
            unsigned int v = 0;
            if ((unsigned)iy < 64u && (unsigned)ix < 64u)
                v = XHL[(((long)b * 256 + c) * 64 + iy) * 64 + ix];
            aR[i] = v;
        }
    };
    auto storeA = [&]() {
        #pragma unroll
        for (int i = 0; i < 8; i++) {
            int idx = i * 256 + tid;
            int kl = idx & 31, ml = idx >> 5;
            Ah[ml * 40 + kl] = (unsigned short)(aR[i] & 0xffffu);
            Al[ml * 40 + kl] = (unsigned short)(aR[i] >> 16);
        }
    };
    auto loadB = [&](int k0) {
        bhR = *(const uint4*)(WH + (long)(n0 + bn) * 4096 + (k0 + bk));
        blR = *(const uint4*)(WL + (long)(n0 + bn) * 4096 + (k0 + bk));
    };

    f32x4 acc[4] = {};
    loadA(0); loadB(0);
    for (int k0 = 0; k0 < 4096; k0 += 32) {
        storeA();
        *(uint4*)(&Bh[bn * 40 + bk]) = bhR;
        *(uint4*)(&Bl[bn * 40 + bk]) = blR;
        __syncthreads();
        if (k0 + 32 < 4096) { loadA(k0 + 32); loadB(k0 + 32); }
        bf16x8 afh = *(const bf16x8*)(&Ah[(w * 16 + l15) * 40 + q * 8]);
        bf16x8 afl = *(const bf16x8*)(&Al[(w * 16 + l15) * 40 + q * 8]);
        #pragma unroll
        for (int j4 = 0; j4 < 4; j4++) {
            bf16x8 bfh = *(const bf16x8*)(&Bh[(j4 * 16 + l15) * 40 + q * 8]);
            bf16x8 bfl = *(const bf16x8*)(&Bl[(j4 * 16 + l15) * 40 + q * 8]);
            acc[j4] = __builtin_amdgcn_mfma_f32_16x16x32_bf16(afh, bfh, acc[j4], 0, 0, 0);
            acc[j4] = __builtin_amdgcn_mfma_f32_16x16x32_bf16(afh, bfl, acc[j4], 0, 0, 0);
            acc[j4] = __builtin_amdgcn_mfma_f32_16x16x32_bf16(afl, bfh, acc[j4], 0, 0, 0);
        }
        __syncthreads();
    }
    #pragma unroll
    for (int j4 = 0; j4 < 4; j4++) {
        int n = n0 + j4 * 16 + l15;
        #pragma unroll
        for (int r = 0; r < 4; r++) {
            int m = m0 + w * 16 + q * 4 + r;
            C[(long)m * 256 + n] = acc[j4][r] + e0[n];
        }
    }
}

// ---------------- fp32 GEMM (coarse qkv / fine qkv): C[m,n] = sum_k A[m,k]*B[n,k] ----------------
template<int EPI>
__global__ __launch_bounds__(256) void gemm_k(
    const float* __restrict__ A, const float* __restrict__ B, float* __restrict__ C,
    int K, int sAm, int sBn,
    const float* __restrict__ e0,
    float* __restrict__ o1, float* __restrict__ o2)
{
    __shared__ float As[16][68];
    __shared__ float Bs[16][68];
    int m0 = blockIdx.y * 64;
    int n0 = blockIdx.x * 64;
    int tid = threadIdx.x;
    int tx = tid & 15, ty = tid >> 4;
    int l4 = tid >> 2, kq = (tid & 3) * 4;
    float4 aR, bR;

    auto loadA = [&](int k0) { aR = *(const float4*)(A + (long)(m0 + l4) * sAm + (k0 + kq)); };
    auto loadB = [&](int k0) { bR = *(const float4*)(B + (long)(n0 + l4) * sBn + (k0 + kq)); };

    float acc[4][4] = {};
    loadA(0); loadB(0);
    for (int k0 = 0; k0 < K; k0 += 16) {
        As[kq + 0][l4] = aR.x; As[kq + 1][l4] = aR.y; As[kq + 2][l4] = aR.z; As[kq + 3][l4] = aR.w;
        Bs[kq + 0][l4] = bR.x; Bs[kq + 1][l4] = bR.y; Bs[kq + 2][l4] = bR.z; Bs[kq + 3][l4] = bR.w;
        __syncthreads();
        if (k0 + 16 < K) { loadA(k0 + 16); loadB(k0 + 16); }
        #pragma unroll
        for (int kk = 0; kk < 16; ++kk) {
            float4 av = *reinterpret_cast<const float4*>(&As[kk][ty * 4]);
            float4 bv = *reinterpret_cast<const float4*>(&Bs[kk][tx * 4]);
            float a[4] = {av.x, av.y, av.z, av.w};
            float b[4] = {bv.x, bv.y, bv.z, bv.w};
            #pragma unroll
            for (int i = 0; i < 4; i++)
                #pragma unroll
                for (int j = 0; j < 4; j++)
                    acc[i][j] += a[i] * b[j];
        }
        __syncthreads();
    }
    #pragma unroll
    for (int i = 0; i < 4; i++) {
        int m = m0 + ty * 4 + i;
        #pragma unroll
        for (int j = 0; j < 4; j++) {
            int n = n0 + tx * 4 + j;
            float v = acc[i][j] + e0[n];
            int bh, tok;
            if (EPI == 2) { int bi = m >> 12; int h = m & 3; tok = (m >> 2) & 1023; bh = bi * 4 + h; }
            else          { bh = m >> 10; tok = m & 1023; }
            long base = ((long)bh * 1024 + tok) * 64;
            if (n < 64) C[base + n] = v;
            else if (n < 128) o1[base + (n - 64)] = v;
            else o2[base + (n - 128)] = v;
        }
    }
}

// ---------------- bf16 MFMA GEMM (post-topk): C[m,n] = sum_k A[m,k]*B[n,k] ----------------
template<int EPI, int AMODE>
__global__ __launch_bounds__(256) void gemm_mfma(
    const float* __restrict__ A, const unsigned short* __restrict__ Bb, float* __restrict__ C,
    int K, long sAz, long sBz, int sAk, int sBn,
    const float* __restrict__ e0, const float* __restrict__ e1,
    void* __restrict__ ob, const int* __restrict__ flagp)
{
    __shared__ __align__(16) unsigned short Asb[64 * 40];
    __shared__ __align__(16) unsigned short Bsb[64 * 40];
    int z = blockIdx.z;
    if (AMODE == 0) A += (long)z * sAz;
    Bb += (long)z * sBz;
    int m0 = blockIdx.y * 64, n0 = blockIdx.x * 64;
    int tid = threadIdx.x;
    int w = tid >> 6, l = tid & 63;
    int l15 = l & 15, q = l >> 4;
    float aR[8];
    uint4 bR;

    auto loadA = [&](int k0) {
        if (AMODE == 0) {
            #pragma unroll
            for (int i = 0; i < 8; i++) {
                int idx = i * 256 + tid;
                int ml = idx & 63, kl = idx >> 6;
                aR[i] = A[(long)(k0 + kl) * sAk + (m0 + ml)];
            }
        } else {  // gather from OUTC [bh][tok][d]; m=(b,y,x), k=(ci,j), cls=z
            #pragma unroll
            for (int i = 0; i < 8; i++) {
                int idx = i * 256 + tid;
                int kl = idx & 31, ml = idx >> 5;
                int m = m0 + ml, k = k0 + kl;
                int b = m >> 10, y = (m >> 5) & 31, x2 = m & 31;
                int ci = k >> 2, j = k & 3;
                int pa = z >> 1, pb = z & 1;
                int jy = j >> 1, jx = j & 1;
                int dy = (pa == 0) ? (jy ? -1 : 0) : (jy ? 1 : 0);
                int dx = (pb == 0) ? (jx ? -1 : 0) : (jx ? 1 : 0);
                int yy = y + dy, xx = x2 + dx;
                float val = 0.f;
                if ((unsigned)yy < 32u && (unsigned)xx < 32u)
                    val = A[(((long)b * 4 + (ci >> 6)) * 1024 + yy * 32 + xx) * 64 + (ci & 63)];
                aR[i] = val;
            }
        }
    };
    auto storeA = [&]() {
        #pragma unroll
        for (int i = 0; i < 8; i++) {
            int idx = i * 256 + tid;
            int ml, kl;
            if (AMODE == 0) { ml = idx & 63; kl = idx >> 6; }
            else            { kl = idx & 31; ml = idx >> 5; }
            Asb[ml * 40 + kl] = f2bf(aR[i]);
        }
    };
    int bn = tid >> 2, bk = (tid & 3) * 8;
    auto loadB = [&](int k0) {
        bR = *(const uint4*)(Bb + (long)(n0 + bn) * sBn + (k0 + bk));
    };

    f32x4 acc[4] = {};
    loadA(0); loadB(0);
    for (int k0 = 0; k0 < K; k0 += 32) {
        storeA();
        *(uint4*)(&Bsb[bn * 40 + bk]) = bR;
        __syncthreads();
        if (k0 + 32 < K) { loadA(k0 + 32); loadB(k0 + 32); }
        bf16x8 af = *(const bf16x8*)(&Asb[(w * 16 + l15) * 40 + q * 8]);
        #pragma unroll
        for (int j4 = 0; j4 < 4; j4++) {
            bf16x8 bf = *(const bf16x8*)(&Bsb[(j4 * 16 + l15) * 40 + q * 8]);
            acc[j4] = __builtin_amdgcn_mfma_f32_16x16x32_bf16(af, bf, acc[j4], 0, 0, 0);
        }
        __syncthreads();
    }
    int oflag = (EPI == 5) ? *flagp : 0;
    #pragma unroll
    for (int j4 = 0; j4 < 4; j4++) {
        int n = n0 + j4 * 16 + l15;
        #pragma unroll
        for (int r = 0; r < 4; r++) {
            int m = m0 + w * 16 + q * 4 + r;
            float v = acc[j4][r];
            if (EPI == 4) {
                v += e0[n];
                int pa = z >> 1, pb = z & 1;
                int bi = m >> 10, y = (m >> 5) & 31, x2 = m & 31;
                C[(((long)bi * 256 + n) * 64 + (2 * y + pa)) * 64 + (2 * x2 + pb)] = v;
            } else {
                v = relu6(v * e0[n] + e1[n]);
                long oidx = (long)z * 1048576 + (long)n * 4096 + m;
                if (oflag) ((bf16*)ob)[oidx] = __float2bfloat16(v);
                else       ((float*)ob)[oidx] = v;
            }
        }
    }
}

// ---------------- fused two-pass attention: [bh=32][N=1024][D=64], scale 1/8 folded into Q ----------------
template<bool SCORE>
__global__ __launch_bounds__(256) void attn_kernel(
    const float* __restrict__ Q, const float* __restrict__ K, const float* __restrict__ V,
    float* __restrict__ O, float* __restrict__ PSC)
{
    __shared__ __align__(16) float QT[64 * 68];
    __shared__ __align__(16) float KV[64 * 68];
    __shared__ __align__(16) float Ps[64 * 68];
    __shared__ float colpart[16 * 64];
    int bh = blockIdx.y, rt = blockIdx.x;
    int tid = threadIdx.x;
    int tx = tid & 15, ty = tid >> 4;
    long qbase = ((long)bh * 1024 + rt * 64) * 64;
    for (int q = tid; q < 1024; q += 256) {
        int r = q >> 4, d4 = (q & 15) * 4;
        float4 v4 = *(const float4*)(Q + qbase + r * 64 + d4);
        QT[(d4 + 0) * 68 + r] = v4.x * 0.125f;
        QT[(d4 + 1) * 68 + r] = v4.y * 0.125f;
        QT[(d4 + 2) * 68 + r] = v4.z * 0.125f;
        QT[(d4 + 3) * 68 + r] = v4.w * 0.125f;
    }
    float m[4], l[4];
    #pragma unroll
    for (int i = 0; i < 4; i++) { m[i] = -1e30f; l[i] = 0.f; }
    __syncthreads();

    for (int t = 0; t < 16; ++t) {
        long kbase = ((long)bh * 1024 + t * 64) * 64;
        for (int q = tid; q < 1024; q += 256) {
            int c = q >> 4, d4 = (q & 15) * 4;
            float4 v4 = *(const float4*)(K + kbase + c * 64 + d4);
            KV[(d4 + 0) * 68 + c] = v4.x;
            KV[(d4 + 1) * 68 + c] = v4.y;
            KV[(d4 + 2) * 68 + c] = v4.z;
            KV[(d4 + 3) * 68 + c] = v4.w;
        }
        __syncthreads();
        float zv[4][4] = {};
        for (int d = 0; d < 64; ++d) {
            float4 qa = *(const float4*)(QT + d * 68 + ty * 4);
            float4 kb = *(const float4*)(KV + d * 68 + tx * 4);
            float a[4] = {qa.x, qa.y, qa.z, qa.w};
            float b[4] = {kb.x, kb.y, kb.z, kb.w};
            #pragma unroll
            for (int i = 0; i < 4; i++)
                #pragma unroll
                for (int j = 0; j < 4; j++)
                    zv[i][j] += a[i] * b[j];
        }
        #pragma unroll
        for (int i = 0; i < 4; i++) {
            float tm = fmaxf(fmaxf(zv[i][0], zv[i][1]), fmaxf(zv[i][2], zv[i][3]));
            for (int off = 1; off < 16; off <<= 1) tm = fmaxf(tm, __shfl_xor(tm, off, 16));
            float mn = fmaxf(m[i], tm);
            float ss = __expf(zv[i][0] - mn) + __expf(zv[i][1] - mn) + __expf(zv[i][2] - mn) + __expf(zv[i][3] - mn);
            for (int off = 1; off < 16; off <<= 1) ss += __shfl_xor(ss, off, 16);
            l[i] = l[i] * __expf(m[i] - mn) + ss;
            m[i] = mn;
        }
        __syncthreads();
    }
    float linv[4];
    #pragma unroll
    for (int i = 0; i < 4; i++) linv[i] = 1.f / l[i];

    float Oa[4][4] = {};
    for (int t = 0; t < 16; ++t) {
        long kbase = ((long)bh * 1024 + t * 64) * 64;
        for (int q = tid; q < 1024; q += 256) {
            int c = q >> 4, d4 = (q & 15) * 4;
            float4 v4 = *(const float4*)(K + kbase + c * 64 + d4);
            KV[(d4 + 0) * 68 + c] = v4.x;
            KV[(d4 + 1) * 68 + c] = v4.y;
            KV[(d4 + 2) * 68 + c] = v4.z;
            KV[(d4 + 3) * 68 + c] = v4.w;
        }
        __syncthreads();
        float zv[4][4] = {};
        for (int d = 0; d < 64; ++d) {
            float4 qa = *(const float4*)(QT + d * 68 + ty * 4);
            float4 kb = *(const float4*)(KV + d * 68 + tx * 4);
            float a[4] = {qa.x, qa.y, qa.z, qa.w};
            float b[4] = {kb.x, kb.y, kb.z, kb.w};
            #pragma unroll
            for (int i = 0; i < 4; i++)
                #pragma unroll
                for (int j = 0; j < 4; j++)
                    zv[i][j] += a[i] * b[j];
        }
        float cs[4] = {0.f, 0.f, 0.f, 0.f};
        #pragma unroll
        for (int i = 0; i < 4; i++)
            #pragma unroll
            for (int j = 0; j < 4; j++) {
                float p = __expf(zv[i][j] - m[i]) * linv[i];
                Ps[(ty * 4 + i) * 68 + tx * 4 + j] = p;
                cs[j] += p;
            }
        if (SCORE) {
            #pragma unroll
            for (int j = 0; j < 4; j++) colpart[ty * 64 + tx * 4 + j] = cs[j];
        }
        __syncthreads();
        if (SCORE && tid < 64) {
            float s = 0.f;
            #pragma unroll
            for (int g = 0; g < 16; g++) s += colpart[g * 64 + tid];
            PSC[((long)(bh * 16 + rt) << 10) + t * 64 + tid] = s;
        }
        for (int q = tid; q < 1024; q += 256) {
            int c = q >> 4, d4 = (q & 15) * 4;
            float4 v4 = *(const float4*)(V + kbase + c * 64 + d4);
            *(float4*)(KV + c * 68 + d4) = v4;
        }
        __syncthreads();
        for (int c = 0; c < 64; ++c) {
            float4 vb = *(const float4*)(KV + c * 68 + tx * 4);
            float b[4] = {vb.x, vb.y, vb.z, vb.w};
            float pv[4];
            #pragma unroll
            for (int i = 0; i < 4; i++) pv[i] = Ps[(ty * 4 + i) * 68 + c];
            #pragma unroll
            for (int i = 0; i < 4; i++)
                #pragma unroll
                for (int j = 0; j < 4; j++)
                    Oa[i][j] += pv[i] * b[j];
        }
        __syncthreads();
    }
    #pragma unroll
    for (int i = 0; i < 4; i++) {
        float4 o4 = make_float4(Oa[i][0], Oa[i][1], Oa[i][2], Oa[i][3]);
        *(float4*)(O + qbase + (ty * 4 + i) * 64 + tx * 4) = o4;
    }
}

__global__ __launch_bounds__(256) void score_reduce_kernel(const float* __restrict__ PSC, float* __restrict__ score) {
    int idx = blockIdx.x * 256 + threadIdx.x;
    int bh = idx >> 10, c = idx & 1023;
    float s = 0.f;
    for (int rt = 0; rt < 16; rt++) s += PSC[((long)(bh * 16 + rt) << 10) + c];
    score[idx] = s;
}

__global__ __launch_bounds__(256) void topk_kernel(const float* __restrict__ score, int* __restrict__ topk) {
    __shared__ float s[1024];
    int z = blockIdx.x; int tid = threadIdx.x;
    for (int i = tid; i < 1024; i += 256) {
        float v = score[z * 1024 + i];
        s[i] = (v == v) ? v : -INFINITY;
    }
    __syncthreads();
    for (int i = tid; i < 1024; i += 256) {
        float si = s[i]; int r = 0;
        for (int j = 0; j < 1024; j++) {
            float sj = s[j];
            r += (sj > si) || (sj == si && j < i);
        }
        if (r < 256) topk[z * 256 + r] = i;
    }
}

__global__ __launch_bounds__(256) void gather_tokf_kernel(const float* __restrict__ coarse,
                                                          const int* __restrict__ topk,
                                                          float* __restrict__ tokf) {
    long idx = (long)blockIdx.x * 256 + threadIdx.x;
    int d = (int)(idx & 63); int t = (int)((idx >> 6) & 3);
    int j = (int)((idx >> 8) & 255); int bh = (int)(idx >> 16);
    int p = topk[bh * 256 + j] & 1023;
    int py = p >> 5, px = p & 31;
    int dy = t >> 1, dx = t & 1;
    int b = bh >> 2, h = bh & 3;
    tokf[idx] = coarse[(((long)b * 256 + h * 64 + d) * 64 + (2 * py + dy)) * 64 + (2 * px + dx)];
}

__global__ __launch_bounds__(256) void scatter_add_kernel(float* __restrict__ coarse,
                                                          const int* __restrict__ topk,
                                                          const float* __restrict__ outf) {
    long idx = (long)blockIdx.x * 256 + threadIdx.x;
    int d = (int)(idx & 63); int t = (int)((idx >> 6) & 3);
    int j = (int)((idx >> 8) & 255); int bh = (int)(idx >> 16);
    int p = topk[bh * 256 + j] & 1023;
    int py = p >> 5, px = p & 31;
    int dy = t >> 1, dx = t & 1;
    int b = bh >> 2, h = bh & 3;
    coarse[(((long)b * 256 + h * 64 + d) * 64 + (2 * py + dy)) * 64 + (2 * px + dx)] += outf[idx];
}

__global__ __launch_bounds__(64) void dw_bn_relu6_kernel(const float* __restrict__ y, const float* __restrict__ w9,
                                                         const float* __restrict__ s1, const float* __restrict__ t1,
                                                         float* __restrict__ out) {
    int gid = blockIdx.x;
    int row = gid & 63; int bc = gid >> 6; int c = bc & 255;
    int x = threadIdx.x;
    const float* base = y + (long)bc * 4096;
    float acc = 0.f;
    #pragma unroll
    for (int ky = 0; ky < 3; ky++) {
        int yy = row + ky - 1;
        if (yy < 0 || yy >= 64) continue;
        #pragma unroll
        for (int kx = 0; kx < 3; kx++) {
            int xx = x + kx - 1;
            if (xx < 0 || xx >= 64) continue;
            acc += base[yy * 64 + xx] * w9[c * 9 + ky * 3 + kx];
        }
    }
    out[(long)gid * 64 + x] = relu6(acc * s1[c] + t1[c]);
}

// ---------------- launch ----------------
extern "C" void kernel_launch(void* const* d_in, const int* in_sizes, int n_in,
                              void* d_out, int out_size, void* d_ws, size_t ws_size,
                              hipStream_t stream) {
    if (ws_size < (size_t)WS_FLOATS * 4) return;

    const void* x      = d_in[0];
    const void* down_w = d_in[1];
    const void* down_b = d_in[2];
    const void* up_w   = d_in[3];
    const void* up_b   = d_in[4];
    const void* wqkv_c = d_in[5];
    const void* bqkv_c = d_in[6];
    const void* wqkv_f = d_in[7];
    const void* bqkv_f = d_in[8];
    const void* dw_w   = d_in[9];
    const void* bn1_g  = d_in[10];
    const void* bn1_b  = d_in[11];
    const void* bn1_m  = d_in[12];
    const void* bn1_v  = d_in[13];
    const void* pw_w   = d_in[14];
    const void* bn2_g  = d_in[15];
    const void* bn2_b  = d_in[16];
    const void* bn2_m  = d_in[17];
    const void* bn2_v  = d_in[18];

    float* ws = (float*)d_ws;
    int* flagp = (int*)(ws + OFF_FLAG);
    dim3 blk(256);

    hipMemsetAsync(flagp, 0, sizeof(int), stream);
    detect_kernel<<<1, blk, 0, stream>>>(x, flagp);

    // split x and down_w into bf16 hi/lo
    split_pack_kernel<<<32768, blk, 0, stream>>>(x, (unsigned int*)(ws + OFF_XHL), 8388608, flagp);
    split_kernel<<<4096, blk, 0, stream>>>(down_w, (unsigned short*)(ws + OFF_DOWNW),
                                           (unsigned short*)(ws + OFF_DOWNWL), 1048576, flagp);
    cvt_kernel<<<1, blk, 0, stream>>>(down_b, ws + OFF_DOWNB, 256, flagp);
    cvt_kernel<<<1, blk, 0, stream>>>(up_b, ws + OFF_UPB, 256, flagp);
    cvt_kernel<<<1, blk, 0, stream>>>(bqkv_c, ws + OFF_BQKVC, 192, flagp);
    cvt_kernel<<<1, blk, 0, stream>>>(bqkv_f, ws + OFF_BQKVF, 192, flagp);
    cvt_bf16_kernel<<<256, blk, 0, stream>>>(pw_w, (unsigned short*)(ws + OFF_PWW), 65536, flagp);
    cvt_kernel<<<9, blk, 0, stream>>>(dw_w, ws + OFF_DWW, 2304, flagp);
    tqkv_kernel<<<48, blk, 0, stream>>>(wqkv_c, ws + OFF_WQKVC, flagp);
    tqkv_kernel<<<48, blk, 0, stream>>>(wqkv_f, ws + OFF_WQKVF, flagp);
    prep_up_kernel<<<4096, blk, 0, stream>>>(up_w, (unsigned short*)(ws + OFF_UPW4), flagp);
    bn_prep_kernel<<<1, blk, 0, stream>>>(bn1_g, bn1_b, bn1_m, bn1_v, ws + OFF_BN1S, ws + OFF_BN1T, flagp);
    bn_prep_kernel<<<1, blk, 0, stream>>>(bn2_g, bn2_b, bn2_m, bn2_v, ws + OFF_BN2S, ws + OFF_BN2T, flagp);

    // down conv (bf16x2 MFMA, topk-safe): M=8192, N=256, K=4096 -> xd NHWC
    gemm_mfma_x2<<<dim3(4, 128, 1), blk, 0, stream>>>((const unsigned int*)(ws + OFF_XHL),
        (const unsigned short*)(ws + OFF_DOWNW), (const unsigned short*)(ws + OFF_DOWNWL),
        ws + OFF_XDHWC, ws + OFF_DOWNB);

    // coarse qkv (fp32): M=32768, N=192, K=64 -> Q, K, V [bh][tok][d]
    gemm_k<2><<<dim3(3, 512, 1), blk, 0, stream>>>(ws + OFF_XDHWC, ws + OFF_WQKVC, ws + OFF_Q,
        64, 64, 64, ws + OFF_BQKVC, ws + OFF_KK, ws + OFF_V);

    // coarse fused attention (+ colsums) -> OUTC, PSC
    attn_kernel<true><<<dim3(16, 32), blk, 0, stream>>>(ws + OFF_Q, ws + OFF_KK, ws + OFF_V,
        ws + OFF_OUTC, ws + OFF_PSC);
    score_reduce_kernel<<<128, blk, 0, stream>>>(ws + OFF_PSC, ws + OFF_SCORE);
    topk_kernel<<<32, blk, 0, stream>>>(ws + OFF_SCORE, (int*)(ws + OFF_TOPK));

    // up conv (bf16 MFMA, post-topk): M=8192, N=256, K=1024, z=cls -> coarse NCHW (overwrites XHL)
    gemm_mfma<4, 2><<<dim3(4, 128, 4), blk, 0, stream>>>(ws + OFF_OUTC, (unsigned short*)(ws + OFF_UPW4),
        ws + OFF_COARSE, 1024, 0, 262144, 0, 1024, ws + OFF_UPB, nullptr, nullptr, flagp);

    // fine attention (fp32)
    gather_tokf_kernel<<<8192, blk, 0, stream>>>(ws + OFF_COARSE, (const int*)(ws + OFF_TOPK), ws + OFF_XDHWC);
    gemm_k<3><<<dim3(3, 512, 1), blk, 0, stream>>>(ws + OFF_XDHWC, ws + OFF_WQKVF, ws + OFF_Q,
        64, 64, 64, ws + OFF_BQKVF, ws + OFF_KK, ws + OFF_V);
    attn_kernel<false><<<dim3(16, 32), blk, 0, stream>>>(ws + OFF_Q, ws + OFF_KK, ws + OFF_V,
        ws + OFF_OUTC, nullptr);
    scatter_add_kernel<<<8192, blk, 0, stream>>>(ws + OFF_COARSE, (const int*)(ws + OFF_TOPK), ws + OFF_OUTC);

    // depthwise + bn1 + relu6 -> T1
    dw_bn_relu6_kernel<<<131072, dim3(64), 0, stream>>>(ws + OFF_COARSE, ws + OFF_DWW,
        ws + OFF_BN1S, ws + OFF_BN1T, ws + OFF_T1);

    // pointwise + bn2 + relu6 (bf16 MFMA) -> d_out: M=4096, N=256, K=256, z=batch
    gemm_mfma<5, 0><<<dim3(4, 64, 8), blk, 0, stream>>>(ws + OFF_T1, (unsigned short*)(ws + OFF_PWW),
        nullptr, 256, 1048576, 0, 4096, 256, ws + OFF_BN2S, ws + OFF_BN2T, d_out, flagp);
}